// Round 1
// baseline (526.598 us; speedup 1.0000x reference)
//
#include <hip/hip_runtime.h>
#include <hip/hip_bf16.h>

typedef __bf16 bf16;
typedef __attribute__((ext_vector_type(8))) __bf16 bf16x8;
typedef __attribute__((ext_vector_type(4))) float f32x4;

#define D_MODEL 1024
#define NHEADS  16
#define DK      64
#define DFF     4096
#define BATCH   4
#define SEQ     2048
#define NTOK    (BATCH*SEQ)   // 8192
#define QSCALE  0.18033688011112042f   // 0.125 * log2(e)

__device__ __forceinline__ void gload16(const bf16* g, bf16* l) {
    __builtin_amdgcn_global_load_lds((const __attribute__((address_space(1))) void*)g,
                                     (__attribute__((address_space(3))) void*)l, 16, 0, 0);
}

// ---------------------------------------------------------------- transpose+cast (4x 1024^2 fused on z)
__global__ __launch_bounds__(256) void transpose_cast4(
    const float* __restrict__ W0, const float* __restrict__ W1,
    const float* __restrict__ W2, const float* __restrict__ W3,
    bf16* __restrict__ T0, bf16* __restrict__ T1,
    bf16* __restrict__ T2, bf16* __restrict__ T3)
{
    const int z = blockIdx.z;
    const float* W = (z == 0) ? W0 : (z == 1) ? W1 : (z == 2) ? W2 : W3;
    bf16*       Wt = (z == 0) ? T0 : (z == 1) ? T1 : (z == 2) ? T2 : T3;
    const int K = 1024, N = 1024;
    __shared__ float tile[32][33];
    const int tx = threadIdx.x, ty = threadIdx.y;
    const int n0 = blockIdx.x * 32, k0 = blockIdx.y * 32;
#pragma unroll
    for (int i = 0; i < 4; ++i)
        tile[ty + i*8][tx] = W[(size_t)(k0 + ty + i*8) * N + n0 + tx];
    __syncthreads();
#pragma unroll
    for (int i = 0; i < 4; ++i)
        Wt[(size_t)(n0 + ty + i*8) * K + k0 + tx] = (bf16)tile[tx][ty + i*8];
}

__global__ __launch_bounds__(256) void transpose_cast(
    const float* __restrict__ W, bf16* __restrict__ Wt, int K, int N)
{
    __shared__ float tile[32][33];
    const int tx = threadIdx.x, ty = threadIdx.y;
    const int n0 = blockIdx.x * 32, k0 = blockIdx.y * 32;
#pragma unroll
    for (int i = 0; i < 4; ++i)
        tile[ty + i*8][tx] = W[(size_t)(k0 + ty + i*8) * N + n0 + tx];
    __syncthreads();
#pragma unroll
    for (int i = 0; i < 4; ++i)
        Wt[(size_t)(n0 + ty + i*8) * K + k0 + tx] = (bf16)tile[tx][ty + i*8];
}

// ---------------------------------------------------------------- V head-transpose
// Vh[bh][s][64] -> VhT[bh][64][2048]
__global__ __launch_bounds__(256) void transpose_v(
    const bf16* __restrict__ V, bf16* __restrict__ VT)
{
    __shared__ bf16 t[64][72];
    const int bh = blockIdx.y;
    const int s0 = blockIdx.x * 64;
    const int r  = threadIdx.x >> 2;         // 0..63
    const int c0 = (threadIdx.x & 3) * 16;   // 0,16,32,48
    const bf16* Vb = V  + (size_t)bh * SEQ * DK;
    bf16*       Tb = VT + (size_t)bh * DK * SEQ;
#pragma unroll
    for (int i = 0; i < 2; ++i) {
        bf16x8 v = *(const bf16x8*)&Vb[(size_t)(s0 + r) * DK + c0 + i*8];
#pragma unroll
        for (int j = 0; j < 8; ++j) t[c0 + i*8 + j][r] = v[j];
    }
    __syncthreads();
#pragma unroll
    for (int i = 0; i < 2; ++i) {
        bf16x8 o;
#pragma unroll
        for (int j = 0; j < 8; ++j) o[j] = t[r][c0 + i*8 + j];
        *(bf16x8*)&Tb[(size_t)r * SEQ + s0 + c0 + i*8] = o;
    }
}

// ---------------------------------------------------------------- layernorm (fp32 in, bf16 out)
__global__ __launch_bounds__(256) void ln_kernel(
    const float* __restrict__ x, const float* __restrict__ g,
    const float* __restrict__ beta, bf16* __restrict__ out)
{
    const int row = blockIdx.x, tid = threadIdx.x;
    const f32x4* xr = (const f32x4*)(x + (size_t)row * D_MODEL);
    f32x4 v = xr[tid];
    float s  = v[0] + v[1] + v[2] + v[3];
    float s2 = v[0]*v[0] + v[1]*v[1] + v[2]*v[2] + v[3]*v[3];
#pragma unroll
    for (int off = 32; off > 0; off >>= 1) {
        s  += __shfl_down(s,  off, 64);
        s2 += __shfl_down(s2, off, 64);
    }
    __shared__ float red[8];
    const int wave = tid >> 6, lane = tid & 63;
    if (lane == 0) { red[wave] = s; red[wave + 4] = s2; }
    __syncthreads();
    if (tid == 0) {
        float a = red[0] + red[1] + red[2] + red[3];
        float c = red[4] + red[5] + red[6] + red[7];
        float mu  = a * (1.0f / D_MODEL);
        float var = c * (1.0f / D_MODEL) - mu * mu;
        red[0] = mu;
        red[1] = rsqrtf(var + 1e-5f);
    }
    __syncthreads();
    const float mu = red[0], rs = red[1];
    f32x4 gv = ((const f32x4*)g)[tid];
    f32x4 bv = ((const f32x4*)beta)[tid];
    union { bf16 h[4]; uint2 u; } o;
#pragma unroll
    for (int i = 0; i < 4; ++i) o.h[i] = (bf16)((v[i] - mu) * rs * gv[i] + bv[i]);
    *(uint2*)(out + (size_t)row * D_MODEL + tid * 4) = o.u;
}

// ---------------------------------------------------------------- bf16 GEMM, 128x128 tile, BK=32 (legacy; O-proj only)
template<int EPI>
__global__ __launch_bounds__(256, 2) void gemm_bf16(
    const bf16* __restrict__ A, const bf16* __restrict__ Bt,
    const float* __restrict__ bias, const float* __restrict__ bias2,
    const float* __restrict__ bias3, const float* __restrict__ resid,
    void* __restrict__ outp, int M, int N, int K)
{
    __shared__ __align__(16) bf16 As[128 * 32];
    __shared__ __align__(16) bf16 Bs[128 * 32];
    const int tid  = threadIdx.x;
    const int wave = tid >> 6, lane = tid & 63;
    const int quad = lane >> 4, l16 = lane & 15;
    const int wr = wave >> 1, wc = wave & 1;
    const int m0 = blockIdx.x * 128, n0 = blockIdx.y * 128;

    const int r0 = wave * 32 + (lane >> 2);
    const int r1 = r0 + 16;
    const int u0 = ((lane & 3) - ((r0 >> 1) & 3)) & 3;
    const int u1 = ((lane & 3) - ((r1 >> 1) & 3)) & 3;
    const bf16* gA0 = A  + (size_t)(m0 + r0) * K + u0 * 8;
    const bf16* gA1 = A  + (size_t)(m0 + r1) * K + u1 * 8;
    const bf16* gB0 = Bt + (size_t)(n0 + r0) * K + u0 * 8;
    const bf16* gB1 = Bt + (size_t)(n0 + r1) * K + u1 * 8;
    bf16* lA0 = As + wave * 1024;
    bf16* lA1 = As + wave * 1024 + 512;
    bf16* lB0 = Bs + wave * 1024;
    bf16* lB1 = Bs + wave * 1024 + 512;

    int aoff[4], boff[4];
#pragma unroll
    for (int i = 0; i < 4; ++i) {
        const int ra = wr * 64 + i * 16 + l16;
        aoff[i] = ra * 32 + ((quad + ((ra >> 1) & 3)) & 3) * 8;
        const int rb = wc * 64 + i * 16 + l16;
        boff[i] = rb * 32 + ((quad + ((rb >> 1) & 3)) & 3) * 8;
    }

    const f32x4 vzero = {0.f, 0.f, 0.f, 0.f};
    f32x4 acc[4][4];
#pragma unroll
    for (int i = 0; i < 4; ++i)
#pragma unroll
        for (int j = 0; j < 4; ++j) acc[i][j] = vzero;

    for (int k0 = 0; k0 < K; k0 += 32) {
        __syncthreads();
        gload16(gA0 + k0, lA0);
        gload16(gA1 + k0, lA1);
        gload16(gB0 + k0, lB0);
        gload16(gB1 + k0, lB1);
        __syncthreads();
        bf16x8 af[4], bfr[4];
#pragma unroll
        for (int i = 0; i < 4; ++i) af[i]  = *(const bf16x8*)&As[aoff[i]];
#pragma unroll
        for (int j = 0; j < 4; ++j) bfr[j] = *(const bf16x8*)&Bs[boff[j]];
#pragma unroll
        for (int i = 0; i < 4; ++i)
#pragma unroll
            for (int j = 0; j < 4; ++j)
                acc[i][j] = __builtin_amdgcn_mfma_f32_16x16x32_bf16(af[i], bfr[j], acc[i][j], 0, 0, 0);
    }

#pragma unroll
    for (int i = 0; i < 4; ++i) {
#pragma unroll
        for (int j = 0; j < 4; ++j) {
            const int col = n0 + wc * 64 + j * 16 + l16;
            float bcol, sc = 1.0f;
            if (EPI == 0) {
                const int seg = col >> 10;
                const float* bp = (seg == 0) ? bias : ((seg == 1) ? bias2 : bias3);
                bcol = bp[col & 1023];
                if (seg == 0) sc = QSCALE;
            } else {
                bcol = bias[col];
            }
#pragma unroll
            for (int r = 0; r < 4; ++r) {
                const int row = m0 + wr * 64 + i * 16 + quad * 4 + r;
                const float v = acc[i][j][r] + bcol;
                if (EPI == 0) {
                    const int bb = row >> 11, ss = row & (SEQ - 1);
                    const int hh = (col & 1023) >> 6, dd = col & (DK - 1);
                    const size_t seg = (size_t)(col >> 10);
                    ((bf16*)outp)[seg * 8388608 + (((size_t)(bb * NHEADS + hh)) * SEQ + ss) * DK + dd] = (bf16)(v * sc);
                } else if (EPI == 1) {
                    const size_t idx = (size_t)row * N + col;
                    ((float*)outp)[idx] = v + resid[idx];
                } else {
                    ((bf16*)outp)[(size_t)row * N + col] = (bf16)fmaxf(v, 0.f);
                }
            }
        }
    }
}

// ---------------------------------------------------------------- bf16 GEMM, 256x256 tile, BK=64, 8-wave 8-phase
// 4 phases per K-tile (kk-half x m-half quadrants), counted vmcnt(4) once per K-tile,
// k-split stage units so prefetch lands in regions whose reads finished >=1 barrier ago.
// LDS 128 KiB: A slabs [buf][kk][256][32] @0, B slabs @32768 elements. Chunk-XOR swizzle
// (phys = (k>>3) ^ ((row>>1)&3)) -> ds_read_b128 conflict-free; global src pre-swizzled.
#define PH_WAIT() do { \
    __builtin_amdgcn_s_barrier(); \
    asm volatile("s_waitcnt lgkmcnt(0)" ::: "memory"); \
    __builtin_amdgcn_sched_barrier(0); \
} while (0)

template<int EPI>
__global__ __launch_bounds__(512, 2) void gemm256(
    const bf16* __restrict__ A, const bf16* __restrict__ Bt,
    const float* __restrict__ bias, const float* __restrict__ bias2,
    const float* __restrict__ bias3, const float* __restrict__ resid,
    void* __restrict__ outp, int M, int N, int K)
{
    __shared__ __align__(16) bf16 smem[65536];   // 128 KiB
    const int tid  = threadIdx.x;
    const int wave = tid >> 6, lane = tid & 63;
    const int quad = lane >> 4, l16 = lane & 15;
    const int wr = wave >> 2, wcn = wave & 3;    // 2 x 4 wave grid; per-wave C = 128x64
    const int m0 = blockIdx.x * 256, n0 = blockIdx.y * 256;
    const int NT = K >> 6;

    // staging constants: slot -> (row, phys chunk); global src pre-swizzled (clog = cphys ^ ((r>>1)&3))
    const bf16* gA[2]; const bf16* gB[2]; int ldsOff[2];
#pragma unroll
    for (int l = 0; l < 2; ++l) {
        const int slot = tid + l * 512;
        const int r = slot >> 2;
        const int clog = (slot & 3) ^ ((r >> 1) & 3);
        gA[l] = A  + (size_t)(m0 + r) * K + clog * 8;
        gB[l] = Bt + (size_t)(n0 + r) * K + clog * 8;
        ldsOff[l] = (wave * 64 + l * 512) * 8;   // wave-uniform elem offset; HW adds lane*16B
    }

    auto stageA = [&](int buf, int t, int kk) {
        bf16* dst = smem + (buf * 2 + kk) * 8192;
#pragma unroll
        for (int l = 0; l < 2; ++l) gload16(gA[l] + t * 64 + kk * 32, dst + ldsOff[l]);
    };
    auto stageB = [&](int buf, int t, int kk) {
        bf16* dst = smem + 32768 + (buf * 2 + kk) * 8192;
#pragma unroll
        for (int l = 0; l < 2; ++l) gload16(gB[l] + t * 64 + kk * 32, dst + ldsOff[l]);
    };

    // ds_read fragment bases ((row>>1)&3 == (l16>>1)&3 for all frags)
    const int cswz  = (quad ^ ((l16 >> 1) & 3)) * 8;
    const int aBase = (wr * 128 + l16) * 32 + cswz;
    const int bBase = (wcn * 64 + l16) * 32 + cswz;

    f32x4 acc[8][4];
    const f32x4 vzero = {0.f, 0.f, 0.f, 0.f};
#pragma unroll
    for (int i = 0; i < 8; ++i)
#pragma unroll
        for (int j = 0; j < 4; ++j) acc[i][j] = vzero;

    // prologue: tile0 all 4 units + tile1 kk0 units, then guarantee tile0 (last 2 units may fly)
    stageA(0, 0, 0); stageB(0, 0, 0);
    stageA(0, 0, 1); stageB(0, 0, 1);
    if (NT > 1) {
        stageA(1, 1, 0); stageB(1, 1, 0);
        asm volatile("s_waitcnt vmcnt(4)" ::: "memory");
    } else {
        asm volatile("s_waitcnt vmcnt(0)" ::: "memory");
    }
    __builtin_amdgcn_s_barrier();

    bf16x8 af[4], bfr[4];
#define GMM_MFMA(mh) do { \
    __builtin_amdgcn_s_setprio(1); \
    _Pragma("unroll") \
    for (int i_ = 0; i_ < 4; ++i_) { \
        _Pragma("unroll") \
        for (int j_ = 0; j_ < 4; ++j_) \
            acc[(mh)*4 + i_][j_] = __builtin_amdgcn_mfma_f32_16x16x32_bf16(af[i_], bfr[j_], acc[(mh)*4 + i_][j_], 0, 0, 0); \
    } \
    __builtin_amdgcn_s_setprio(0); \
    __builtin_amdgcn_s_barrier(); \
} while (0)

#pragma unroll 1
    for (int t = 0; t < NT; ++t) {
        const int buf = t & 1;
        const bf16* As0 = smem + buf * 16384;            // kk0 slab
        const bf16* As1 = As0 + 8192;                    // kk1 slab
        const bf16* Bs0 = smem + 32768 + buf * 16384;
        const bf16* Bs1 = Bs0 + 8192;

        // phase 1: kk0, mh0  (stage A-kk1(t+1) into other buf; its last read was t-1 p4)
#pragma unroll
        for (int i = 0; i < 4; ++i) af[i]  = *(const bf16x8*)&As0[aBase + i * 512];
#pragma unroll
        for (int j = 0; j < 4; ++j) bfr[j] = *(const bf16x8*)&Bs0[bBase + j * 512];
        if (t + 1 < NT) stageA(buf ^ 1, t + 1, 1);
        PH_WAIT();
        GMM_MFMA(0);

        // phase 2: kk0, mh1  (B kk0 frags reused)
#pragma unroll
        for (int i = 0; i < 4; ++i) af[i] = *(const bf16x8*)&As0[aBase + 2048 + i * 512];
        if (t + 1 < NT) stageB(buf ^ 1, t + 1, 1);
        PH_WAIT();
        GMM_MFMA(1);

        // phase 3: kk1, mh1  (stage A-kk0(t+2) into CURRENT buf: kk0 reads done at p2 barrier)
#pragma unroll
        for (int i = 0; i < 4; ++i) af[i]  = *(const bf16x8*)&As1[aBase + 2048 + i * 512];
#pragma unroll
        for (int j = 0; j < 4; ++j) bfr[j] = *(const bf16x8*)&Bs1[bBase + j * 512];
        if (t + 2 < NT) stageA(buf, t + 2, 0);
        PH_WAIT();
        GMM_MFMA(1);

        // phase 4: kk1, mh0  (counted vmcnt: last 2 units (t+2 kk0) may stay in flight)
#pragma unroll
        for (int i = 0; i < 4; ++i) af[i] = *(const bf16x8*)&As1[aBase + i * 512];
        if (t + 2 < NT) {
            stageB(buf, t + 2, 0);
            asm volatile("s_waitcnt vmcnt(4)" ::: "memory");
        } else {
            asm volatile("s_waitcnt vmcnt(0)" ::: "memory");
        }
        PH_WAIT();
        GMM_MFMA(0);
    }
#undef GMM_MFMA

    // epilogue
#pragma unroll
    for (int mf = 0; mf < 8; ++mf) {
#pragma unroll
        for (int nf = 0; nf < 4; ++nf) {
            const int col = n0 + wcn * 64 + nf * 16 + l16;
            float bcol, sc = 1.0f;
            if (EPI == 0) {
                const int seg = col >> 10;
                const float* bp = (seg == 0) ? bias : ((seg == 1) ? bias2 : bias3);
                bcol = bp[col & 1023];
                if (seg == 0) sc = QSCALE;
            } else {
                bcol = bias[col];
            }
#pragma unroll
            for (int r = 0; r < 4; ++r) {
                const int row = m0 + wr * 128 + mf * 16 + quad * 4 + r;
                const float v = acc[mf][nf][r] + bcol;
                if (EPI == 0) {
                    const int bb = row >> 11, ss = row & (SEQ - 1);
                    const int hh = (col & 1023) >> 6, dd = col & (DK - 1);
                    const size_t seg = (size_t)(col >> 10);
                    ((bf16*)outp)[seg * 8388608 + (((size_t)(bb * NHEADS + hh)) * SEQ + ss) * DK + dd] = (bf16)(v * sc);
                } else if (EPI == 1) {
                    const size_t idx = (size_t)row * N + col;
                    ((float*)outp)[idx] = v + resid[idx];
                } else {
                    ((bf16*)outp)[(size_t)row * N + col] = (bf16)fmaxf(v, 0.f);
                }
            }
        }
    }
}

// ---------------------------------------------------------------- flash attention (causal), S^T layout
__global__ __launch_bounds__(256, 2) void attn_kernel(
    const bf16* __restrict__ Q, const bf16* __restrict__ K,
    const bf16* __restrict__ VT, bf16* __restrict__ out)
{
    const int bh = blockIdx.x;
    const int b = bh >> 4, h = bh & 15;
    const int tid  = threadIdx.x;
    const int wave = tid >> 6, lane = tid & 63;
    const int quad = lane >> 4, l16 = lane & 15;

    __shared__ __align__(16) bf16 smem[32768 + 4 * 1152];
    bf16* Pw = smem + 32768 + wave * 1152;

    const bf16* Qb = Q  + (size_t)bh * SEQ * DK;
    const bf16* Kb = K  + (size_t)bh * SEQ * DK;
    const bf16* Vb = VT + (size_t)bh * DK * SEQ;

    int goK[4], goV[4], lo[4];
#pragma unroll
    for (int i = 0; i < 4; ++i) {
        const int U = (wave * 4 + i) * 64 + lane;
        const int rK = U >> 3, uK = (U & 7) ^ (rK & 7);
        goK[i] = rK * DK + uK * 8;
        const int rV = U >> 4, usw = U & 15;
        const int uV = (usw & 8) | ((usw & 7) ^ (rV & 7));
        goV[i] = rV * SEQ + uV * 8;
        lo[i]  = (wave * 4 + i) * 512;
    }

    auto stage = [&](int buf, int t) {
        const bf16* kp = Kb + (size_t)(t * 128) * DK;
        const bf16* vp = Vb + t * 128;
        bf16* kb = smem + buf * 8192;
        bf16* vb = smem + 16384 + buf * 8192;
#pragma unroll
        for (int i = 0; i < 4; ++i) gload16(kp + goK[i], kb + lo[i]);
#pragma unroll
        for (int i = 0; i < 4; ++i) gload16(vp + goV[i], vb + lo[i]);
    };

    const f32x4 vzero = {0.f, 0.f, 0.f, 0.f};
    int g = 0;
    stage(0, 0);

    for (int phase = 0; phase < 2; ++phase) {
        const int qt = phase ? (int)blockIdx.y : 15 - (int)blockIdx.y;
        const int qw = qt * 128 + wave * 32;

        bf16x8 qf[2][2];
#pragma unroll
        for (int qi = 0; qi < 2; ++qi)
#pragma unroll
            for (int kk = 0; kk < 2; ++kk)
                qf[qi][kk] = *(const bf16x8*)&Qb[(size_t)(qw + qi*16 + l16) * DK + kk*32 + quad*8];

        f32x4 Oacc[2][4];
        float m_[2], l_[2];
#pragma unroll
        for (int qi = 0; qi < 2; ++qi) {
            m_[qi] = -1.0e30f; l_[qi] = 0.f;
#pragma unroll
            for (int dj = 0; dj < 4; ++dj) Oacc[qi][dj] = vzero;
        }

        for (int t = 0; t <= qt; ++t, ++g) {
            const int cur = g & 1;
            __syncthreads();
            if (t < qt)            stage(cur ^ 1, t + 1);
            else if (phase == 0)   stage(cur ^ 1, 0);
            const bf16* kb = smem + cur * 8192;
            const bf16* vb = smem + 16384 + cur * 8192;
            const int kv0 = t * 128;

            f32x4 sv[8][2];
#pragma unroll
            for (int kvt = 0; kvt < 8; ++kvt) {
                const int R = kvt*16 + l16, rx = R & 7;
                bf16x8 kf0 = *(const bf16x8*)&kb[R*64 + (quad ^ rx)*8];
                bf16x8 kf1 = *(const bf16x8*)&kb[R*64 + (((quad + 4) & 7) ^ rx)*8];
#pragma unroll
                for (int qi = 0; qi < 2; ++qi) {
                    f32x4 tacc = vzero;
                    tacc = __builtin_amdgcn_mfma_f32_16x16x32_bf16(kf0, qf[qi][0], tacc, 0, 0, 0);
                    tacc = __builtin_amdgcn_mfma_f32_16x16x32_bf16(kf1, qf[qi][1], tacc, 0, 0, 0);
                    sv[kvt][qi] = tacc;
                }
            }

            if (t == qt) {
#pragma unroll
                for (int kvt = 0; kvt < 8; ++kvt)
#pragma unroll
                    for (int qi = 0; qi < 2; ++qi)
#pragma unroll
                        for (int r = 0; r < 4; ++r) {
                            const int kv = kv0 + kvt*16 + quad*4 + r;
                            const int q  = qw + qi*16 + l16;
                            if (kv > q) sv[kvt][qi][r] = -1.0e30f;
                        }
            }

#pragma unroll
            for (int qi = 0; qi < 2; ++qi) {
                float mx = sv[0][qi][0];
#pragma unroll
                for (int kvt = 0; kvt < 8; ++kvt)
#pragma unroll
                    for (int r = 0; r < 4; ++r) mx = fmaxf(mx, sv[kvt][qi][r]);
                mx = fmaxf(mx, __shfl_xor(mx, 16, 64));
                mx = fmaxf(mx, __shfl_xor(mx, 32, 64));
                const float newm  = fmaxf(m_[qi], mx);
                const float alpha = exp2f(m_[qi] - newm);
                m_[qi] = newm;
                float rs = 0.f;
#pragma unroll
                for (int kvt = 0; kvt < 8; ++kvt)
#pragma unroll
                    for (int r = 0; r < 4; ++r) {
                        const float p = exp2f(sv[kvt][qi][r] - newm);
                        sv[kvt][qi][r] = p;
                        rs += p;
                    }
                rs += __shfl_xor(rs, 16, 64);
                rs += __shfl_xor(rs, 32, 64);
                l_[qi] = l_[qi] * alpha + rs;
#pragma unroll
                for (int dj = 0; dj < 4; ++dj) Oacc[qi][dj] *= alpha;
            }

#pragma unroll
            for (int c2 = 0; c2 < 4; ++c2) {
#pragma unroll
                for (int qi = 0; qi < 2; ++qi)
#pragma unroll
                    for (int kl = 0; kl < 2; ++kl) {
                        union { bf16 h[4]; unsigned long long u; } pk;
                        const f32x4 s = sv[c2*2 + kl][qi];
#pragma unroll
                        for (int r = 0; r < 4; ++r) pk.h[r] = (bf16)s[r];
                        *(unsigned long long*)&Pw[(qi*16 + l16)*36 + kl*16 + quad*4] = pk.u;
                    }
                bf16x8 vf[4];
#pragma unroll
                for (int dj = 0; dj < 4; ++dj) {
                    const int R = dj*16 + l16;
                    const int u = c2*4 + quad;
                    const int usw = (u & 8) | ((u & 7) ^ (R & 7));
                    vf[dj] = *(const bf16x8*)&vb[R*128 + usw*8];
                }
#pragma unroll
                for (int qi = 0; qi < 2; ++qi) {
                    bf16x8 pf = *(const bf16x8*)&Pw[(qi*16 + l16)*36 + quad*8];
#pragma unroll
                    for (int dj = 0; dj < 4; ++dj)
                        Oacc[qi][dj] = __builtin_amdgcn_mfma_f32_16x16x32_bf16(vf[dj], pf, Oacc[qi][dj], 0, 0, 0);
                }
            }
        }

        const float inv0 = 1.0f / l_[0], inv1 = 1.0f / l_[1];
#pragma unroll
        for (int dh = 0; dh < 2; ++dh) {
#pragma unroll
            for (int qi = 0; qi < 2; ++qi) {
                const float inv = qi ? inv1 : inv0;
#pragma unroll
                for (int djl = 0; djl < 2; ++djl) {
                    const int dj = dh*2 + djl;
                    union { bf16 h[4]; unsigned long long u; } ok;
#pragma unroll
                    for (int r = 0; r < 4; ++r) ok.h[r] = (bf16)(Oacc[qi][dj][r] * inv);
                    *(unsigned long long*)&Pw[(qi*16 + l16)*36 + djl*16 + quad*4] = ok.u;
                }
            }
            const int row = lane >> 1;
#pragma unroll
            for (int it = 0; it < 2; ++it) {
                const int grp = (lane & 1) + 2*it;
                bf16x8 o = *(const bf16x8*)&Pw[row*36 + grp*8];
                *(bf16x8*)&out[((size_t)(b*SEQ + qw - wave*32 + wave*32 + row))*D_MODEL + h*DK + dh*32 + grp*8] = o;
            }
        }
    }
}

// ---------------------------------------------------------------- launch
extern "C" void kernel_launch(void* const* d_in, const int* in_sizes, int n_in,
                              void* d_out, int out_size, void* d_ws, size_t ws_size,
                              hipStream_t stream)
{
    const float* x    = (const float*)d_in[0];
    const float* Wq   = (const float*)d_in[1];
    const float* bq   = (const float*)d_in[2];
    const float* Wk   = (const float*)d_in[3];
    const float* bk   = (const float*)d_in[4];
    const float* Wv   = (const float*)d_in[5];
    const float* bv   = (const float*)d_in[6];
    const float* Wo   = (const float*)d_in[7];
    const float* bo   = (const float*)d_in[8];
    const float* W1   = (const float*)d_in[9];
    const float* b1   = (const float*)d_in[10];
    const float* W2   = (const float*)d_in[11];
    const float* b2   = (const float*)d_in[12];
    const float* ln1g = (const float*)d_in[13];
    const float* ln1b = (const float*)d_in[14];
    const float* ln2g = (const float*)d_in[15];
    const float* ln2b = (const float*)d_in[16];

    char* ws = (char*)d_ws;
    const size_t MB = 1024 * 1024;
    bf16* WTq  = (bf16*)(ws + 0 * MB);
    bf16* WTk  = (bf16*)(ws + 2 * MB);
    bf16* WTv  = (bf16*)(ws + 4 * MB);
    bf16* WTo  = (bf16*)(ws + 6 * MB);
    bf16* WT1  = (bf16*)(ws + 8 * MB);
    bf16* WT2  = (bf16*)(ws + 16 * MB);
    bf16* hbuf = (bf16*)(ws + 24 * MB);
    bf16* VhT  = (bf16*)(ws + 24 * MB);
    bf16* Qh   = (bf16*)(ws + 40 * MB);
    bf16* Kh   = (bf16*)(ws + 56 * MB);
    bf16* Vh   = (bf16*)(ws + 72 * MB);
    bf16* attn = (bf16*)(ws + 88 * MB);
    bf16* ff1  = (bf16*)(ws + 40 * MB);
    float* x2  = (float*)d_out;

    dim3 tb(32, 8);
    transpose_cast4<<<dim3(32, 32, 4), tb, 0, stream>>>(Wq, Wk, Wv, Wo, WTq, WTk, WTv, WTo);
    transpose_cast<<<dim3(128, 32), tb, 0, stream>>>(W1, WT1, 1024, 4096);
    transpose_cast<<<dim3(32, 128), tb, 0, stream>>>(W2, WT2, 4096, 1024);

    ln_kernel<<<NTOK, 256, 0, stream>>>(x, ln1g, ln1b, hbuf);

    // fused QKV: 256^2 8-phase, N=3072
    gemm256<0><<<dim3(32, 12), 512, 0, stream>>>(hbuf, WTq, bq, bk, bv, nullptr, Qh, NTOK, 3072, 1024);

    transpose_v<<<dim3(32, 64), 256, 0, stream>>>(Vh, VhT);

    attn_kernel<<<dim3(64, 8), 256, 0, stream>>>(Qh, Kh, VhT, attn);

    // O-proj: legacy 128^2 (512 blocks, full GPU beats 128-block 256^2 at this shape)
    gemm_bf16<1><<<dim3(64, 8), 256, 0, stream>>>(attn, WTo, bo, nullptr, nullptr, x, x2, NTOK, 1024, 1024);

    ln_kernel<<<NTOK, 256, 0, stream>>>(x2, ln2g, ln2b, hbuf);

    // FF1: 256^2 8-phase, 512 blocks = 2 full occupancy rounds
    gemm256<2><<<dim3(32, 16), 512, 0, stream>>>(hbuf, WT1, b1, nullptr, nullptr, nullptr, ff1, NTOK, 4096, 1024);
    // FF2: 256^2 8-phase (128 blocks; K=4096 deep pipeline)
    gemm256<1><<<dim3(32, 4), 512, 0, stream>>>(ff1, WT2, b2, nullptr, nullptr, x2, x2, NTOK, 1024, 4096);
}

// Round 2
// 500.006 us; speedup vs baseline: 1.0532x; 1.0532x over previous
//
#include <hip/hip_runtime.h>
#include <hip/hip_bf16.h>

typedef __bf16 bf16;
typedef __attribute__((ext_vector_type(8))) __bf16 bf16x8;
typedef __attribute__((ext_vector_type(4))) float f32x4;

#define D_MODEL 1024
#define NHEADS  16
#define DK      64
#define DFF     4096
#define BATCH   4
#define SEQ     2048
#define NTOK    (BATCH*SEQ)   // 8192
#define QSCALE  0.18033688011112042f   // 0.125 * log2(e)

__device__ __forceinline__ void gload16(const bf16* g, bf16* l) {
    __builtin_amdgcn_global_load_lds((const __attribute__((address_space(1))) void*)g,
                                     (__attribute__((address_space(3))) void*)l, 16, 0, 0);
}

// ---------------------------------------------------------------- transpose+cast (4x 1024^2 fused on z)
__global__ __launch_bounds__(256) void transpose_cast4(
    const float* __restrict__ W0, const float* __restrict__ W1,
    const float* __restrict__ W2, const float* __restrict__ W3,
    bf16* __restrict__ T0, bf16* __restrict__ T1,
    bf16* __restrict__ T2, bf16* __restrict__ T3)
{
    const int z = blockIdx.z;
    const float* W = (z == 0) ? W0 : (z == 1) ? W1 : (z == 2) ? W2 : W3;
    bf16*       Wt = (z == 0) ? T0 : (z == 1) ? T1 : (z == 2) ? T2 : T3;
    const int K = 1024, N = 1024;
    __shared__ float tile[32][33];
    const int tx = threadIdx.x, ty = threadIdx.y;
    const int n0 = blockIdx.x * 32, k0 = blockIdx.y * 32;
#pragma unroll
    for (int i = 0; i < 4; ++i)
        tile[ty + i*8][tx] = W[(size_t)(k0 + ty + i*8) * N + n0 + tx];
    __syncthreads();
#pragma unroll
    for (int i = 0; i < 4; ++i)
        Wt[(size_t)(n0 + ty + i*8) * K + k0 + tx] = (bf16)tile[tx][ty + i*8];
}

__global__ __launch_bounds__(256) void transpose_cast(
    const float* __restrict__ W, bf16* __restrict__ Wt, int K, int N)
{
    __shared__ float tile[32][33];
    const int tx = threadIdx.x, ty = threadIdx.y;
    const int n0 = blockIdx.x * 32, k0 = blockIdx.y * 32;
#pragma unroll
    for (int i = 0; i < 4; ++i)
        tile[ty + i*8][tx] = W[(size_t)(k0 + ty + i*8) * N + n0 + tx];
    __syncthreads();
#pragma unroll
    for (int i = 0; i < 4; ++i)
        Wt[(size_t)(n0 + ty + i*8) * K + k0 + tx] = (bf16)tile[tx][ty + i*8];
}

// ---------------------------------------------------------------- V head-transpose
// Vh[bh][s][64] -> VhT[bh][64][2048]
__global__ __launch_bounds__(256) void transpose_v(
    const bf16* __restrict__ V, bf16* __restrict__ VT)
{
    __shared__ bf16 t[64][72];
    const int bh = blockIdx.y;
    const int s0 = blockIdx.x * 64;
    const int r  = threadIdx.x >> 2;         // 0..63
    const int c0 = (threadIdx.x & 3) * 16;   // 0,16,32,48
    const bf16* Vb = V  + (size_t)bh * SEQ * DK;
    bf16*       Tb = VT + (size_t)bh * DK * SEQ;
#pragma unroll
    for (int i = 0; i < 2; ++i) {
        bf16x8 v = *(const bf16x8*)&Vb[(size_t)(s0 + r) * DK + c0 + i*8];
#pragma unroll
        for (int j = 0; j < 8; ++j) t[c0 + i*8 + j][r] = v[j];
    }
    __syncthreads();
#pragma unroll
    for (int i = 0; i < 2; ++i) {
        bf16x8 o;
#pragma unroll
        for (int j = 0; j < 8; ++j) o[j] = t[r][c0 + i*8 + j];
        *(bf16x8*)&Tb[(size_t)r * SEQ + s0 + c0 + i*8] = o;
    }
}

// ---------------------------------------------------------------- layernorm (fp32 in, bf16 out)
__global__ __launch_bounds__(256) void ln_kernel(
    const float* __restrict__ x, const float* __restrict__ g,
    const float* __restrict__ beta, bf16* __restrict__ out)
{
    const int row = blockIdx.x, tid = threadIdx.x;
    const f32x4* xr = (const f32x4*)(x + (size_t)row * D_MODEL);
    f32x4 v = xr[tid];
    float s  = v[0] + v[1] + v[2] + v[3];
    float s2 = v[0]*v[0] + v[1]*v[1] + v[2]*v[2] + v[3]*v[3];
#pragma unroll
    for (int off = 32; off > 0; off >>= 1) {
        s  += __shfl_down(s,  off, 64);
        s2 += __shfl_down(s2, off, 64);
    }
    __shared__ float red[8];
    const int wave = tid >> 6, lane = tid & 63;
    if (lane == 0) { red[wave] = s; red[wave + 4] = s2; }
    __syncthreads();
    if (tid == 0) {
        float a = red[0] + red[1] + red[2] + red[3];
        float c = red[4] + red[5] + red[6] + red[7];
        float mu  = a * (1.0f / D_MODEL);
        float var = c * (1.0f / D_MODEL) - mu * mu;
        red[0] = mu;
        red[1] = rsqrtf(var + 1e-5f);
    }
    __syncthreads();
    const float mu = red[0], rs = red[1];
    f32x4 gv = ((const f32x4*)g)[tid];
    f32x4 bv = ((const f32x4*)beta)[tid];
    union { bf16 h[4]; uint2 u; } o;
#pragma unroll
    for (int i = 0; i < 4; ++i) o.h[i] = (bf16)((v[i] - mu) * rs * gv[i] + bv[i]);
    *(uint2*)(out + (size_t)row * D_MODEL + tid * 4) = o.u;
}

#define PH_WAIT() do { \
    __builtin_amdgcn_s_barrier(); \
    asm volatile("s_waitcnt lgkmcnt(0)" ::: "memory"); \
    __builtin_amdgcn_sched_barrier(0); \
} while (0)

// ---------------------------------------------------------------- bf16 GEMM, 256x256 tile, BK=64, 8-wave 8-phase
// (used where gridDim is a multiple of 256 blocks: FF1)
template<int EPI>
__global__ __launch_bounds__(512, 2) void gemm256(
    const bf16* __restrict__ A, const bf16* __restrict__ Bt,
    const float* __restrict__ bias, const float* __restrict__ bias2,
    const float* __restrict__ bias3, const float* __restrict__ resid,
    void* __restrict__ outp, int M, int N, int K)
{
    __shared__ __align__(16) bf16 smem[65536];   // 128 KiB
    const int tid  = threadIdx.x;
    const int wave = tid >> 6, lane = tid & 63;
    const int quad = lane >> 4, l16 = lane & 15;
    const int wr = wave >> 2, wcn = wave & 3;    // 2 x 4 wave grid; per-wave C = 128x64
    const int m0 = blockIdx.x * 256, n0 = blockIdx.y * 256;
    const int NT = K >> 6;

    const bf16* gA[2]; const bf16* gB[2]; int ldsOff[2];
#pragma unroll
    for (int l = 0; l < 2; ++l) {
        const int slot = tid + l * 512;
        const int r = slot >> 2;
        const int clog = (slot & 3) ^ ((r >> 1) & 3);
        gA[l] = A  + (size_t)(m0 + r) * K + clog * 8;
        gB[l] = Bt + (size_t)(n0 + r) * K + clog * 8;
        ldsOff[l] = (wave * 64 + l * 512) * 8;
    }

    auto stageA = [&](int buf, int t, int kk) {
        bf16* dst = smem + (buf * 2 + kk) * 8192;
#pragma unroll
        for (int l = 0; l < 2; ++l) gload16(gA[l] + t * 64 + kk * 32, dst + ldsOff[l]);
    };
    auto stageB = [&](int buf, int t, int kk) {
        bf16* dst = smem + 32768 + (buf * 2 + kk) * 8192;
#pragma unroll
        for (int l = 0; l < 2; ++l) gload16(gB[l] + t * 64 + kk * 32, dst + ldsOff[l]);
    };

    const int cswz  = (quad ^ ((l16 >> 1) & 3)) * 8;
    const int aBase = (wr * 128 + l16) * 32 + cswz;
    const int bBase = (wcn * 64 + l16) * 32 + cswz;

    f32x4 acc[8][4];
    const f32x4 vzero = {0.f, 0.f, 0.f, 0.f};
#pragma unroll
    for (int i = 0; i < 8; ++i)
#pragma unroll
        for (int j = 0; j < 4; ++j) acc[i][j] = vzero;

    stageA(0, 0, 0); stageB(0, 0, 0);
    stageA(0, 0, 1); stageB(0, 0, 1);
    if (NT > 1) {
        stageA(1, 1, 0); stageB(1, 1, 0);
        asm volatile("s_waitcnt vmcnt(4)" ::: "memory");
    } else {
        asm volatile("s_waitcnt vmcnt(0)" ::: "memory");
    }
    __builtin_amdgcn_s_barrier();

    bf16x8 af[4], bfr[4];
#define GMM_MFMA(mh) do { \
    __builtin_amdgcn_s_setprio(1); \
    _Pragma("unroll") \
    for (int i_ = 0; i_ < 4; ++i_) { \
        _Pragma("unroll") \
        for (int j_ = 0; j_ < 4; ++j_) \
            acc[(mh)*4 + i_][j_] = __builtin_amdgcn_mfma_f32_16x16x32_bf16(af[i_], bfr[j_], acc[(mh)*4 + i_][j_], 0, 0, 0); \
    } \
    __builtin_amdgcn_s_setprio(0); \
    __builtin_amdgcn_s_barrier(); \
} while (0)

#pragma unroll 1
    for (int t = 0; t < NT; ++t) {
        const int buf = t & 1;
        const bf16* As0 = smem + buf * 16384;
        const bf16* As1 = As0 + 8192;
        const bf16* Bs0 = smem + 32768 + buf * 16384;
        const bf16* Bs1 = Bs0 + 8192;

#pragma unroll
        for (int i = 0; i < 4; ++i) af[i]  = *(const bf16x8*)&As0[aBase + i * 512];
#pragma unroll
        for (int j = 0; j < 4; ++j) bfr[j] = *(const bf16x8*)&Bs0[bBase + j * 512];
        if (t + 1 < NT) stageA(buf ^ 1, t + 1, 1);
        PH_WAIT();
        GMM_MFMA(0);

#pragma unroll
        for (int i = 0; i < 4; ++i) af[i] = *(const bf16x8*)&As0[aBase + 2048 + i * 512];
        if (t + 1 < NT) stageB(buf ^ 1, t + 1, 1);
        PH_WAIT();
        GMM_MFMA(1);

#pragma unroll
        for (int i = 0; i < 4; ++i) af[i]  = *(const bf16x8*)&As1[aBase + 2048 + i * 512];
#pragma unroll
        for (int j = 0; j < 4; ++j) bfr[j] = *(const bf16x8*)&Bs1[bBase + j * 512];
        if (t + 2 < NT) stageA(buf, t + 2, 0);
        PH_WAIT();
        GMM_MFMA(1);

#pragma unroll
        for (int i = 0; i < 4; ++i) af[i] = *(const bf16x8*)&As1[aBase + i * 512];
        if (t + 2 < NT) {
            stageB(buf, t + 2, 0);
            asm volatile("s_waitcnt vmcnt(4)" ::: "memory");
        } else {
            asm volatile("s_waitcnt vmcnt(0)" ::: "memory");
        }
        PH_WAIT();
        GMM_MFMA(0);
    }
#undef GMM_MFMA

#pragma unroll
    for (int mf = 0; mf < 8; ++mf) {
#pragma unroll
        for (int nf = 0; nf < 4; ++nf) {
            const int col = n0 + wcn * 64 + nf * 16 + l16;
            float bcol, sc = 1.0f;
            if (EPI == 0) {
                const int seg = col >> 10;
                const float* bp = (seg == 0) ? bias : ((seg == 1) ? bias2 : bias3);
                bcol = bp[col & 1023];
                if (seg == 0) sc = QSCALE;
            } else {
                bcol = bias[col];
            }
#pragma unroll
            for (int r = 0; r < 4; ++r) {
                const int row = m0 + wr * 128 + mf * 16 + quad * 4 + r;
                const float v = acc[mf][nf][r] + bcol;
                if (EPI == 0) {
                    const int bb = row >> 11, ss = row & (SEQ - 1);
                    const int hh = (col & 1023) >> 6, dd = col & (DK - 1);
                    const size_t seg = (size_t)(col >> 10);
                    ((bf16*)outp)[seg * 8388608 + (((size_t)(bb * NHEADS + hh)) * SEQ + ss) * DK + dd] = (bf16)(v * sc);
                } else if (EPI == 1) {
                    const size_t idx = (size_t)row * N + col;
                    ((float*)outp)[idx] = v + resid[idx];
                } else {
                    ((bf16*)outp)[(size_t)row * N + col] = (bf16)fmaxf(v, 0.f);
                }
            }
        }
    }
}

// ---------------------------------------------------------------- bf16 GEMM, 256x128 tile, BK=64, 8-wave, 2 phases/K-tile
// For N-limited shapes (N=1024/3072): grid = (M/256) x (N/128) -> 256+ blocks = full GPU at 1 blk/CU.
// LDS 96 KiB: A [buf][kk][256][32] @0 (4 x 8192 el), B [buf][kk][128][32] @32768 (4 x 4096 el).
// Stage unit: A=2 gloads, B=1 gload (3/kk-half). Counted vmcnt(3) once per K-tile.
template<int EPI>
__global__ __launch_bounds__(512, 2) void gemm256n128(
    const bf16* __restrict__ A, const bf16* __restrict__ Bt,
    const float* __restrict__ bias, const float* __restrict__ bias2,
    const float* __restrict__ bias3, const float* __restrict__ resid,
    void* __restrict__ outp, int M, int N, int K)
{
    __shared__ __align__(16) bf16 smem[49152];   // 96 KiB
    const int tid  = threadIdx.x;
    const int wave = tid >> 6, lane = tid & 63;
    const int quad = lane >> 4, l16 = lane & 15;
    const int wr = wave >> 1, wcn = wave & 1;    // 4 x 2 wave grid; per-wave C = 64x64
    const int m0 = blockIdx.x * 256, n0 = blockIdx.y * 128;
    const int NT = K >> 6;

    // staging: A slots tid + l*512 (rows 0..255), B slot tid (rows 0..127); src pre-swizzled
    const bf16* gA[2]; const bf16* gB0; int ldsOffA[2];
#pragma unroll
    for (int l = 0; l < 2; ++l) {
        const int slot = tid + l * 512;
        const int r = slot >> 2;
        const int clog = (slot & 3) ^ ((r >> 1) & 3);
        gA[l] = A + (size_t)(m0 + r) * K + clog * 8;
        ldsOffA[l] = (wave * 64 + l * 512) * 8;
    }
    {
        const int r = tid >> 2;
        const int clog = (tid & 3) ^ ((r >> 1) & 3);
        gB0 = Bt + (size_t)(n0 + r) * K + clog * 8;
    }
    const int ldsOffB = wave * 512;

    auto stageA = [&](int buf, int t, int kk) {
        bf16* dst = smem + (buf * 2 + kk) * 8192;
#pragma unroll
        for (int l = 0; l < 2; ++l) gload16(gA[l] + t * 64 + kk * 32, dst + ldsOffA[l]);
    };
    auto stageB = [&](int buf, int t, int kk) {
        bf16* dst = smem + 32768 + (buf * 2 + kk) * 4096;
        gload16(gB0 + t * 64 + kk * 32, dst + ldsOffB);
    };

    const int cswz  = (quad ^ ((l16 >> 1) & 3)) * 8;
    const int aBase = (wr * 64 + l16) * 32 + cswz;
    const int bBase = (wcn * 64 + l16) * 32 + cswz;

    f32x4 acc[4][4];
    const f32x4 vzero = {0.f, 0.f, 0.f, 0.f};
#pragma unroll
    for (int i = 0; i < 4; ++i)
#pragma unroll
        for (int j = 0; j < 4; ++j) acc[i][j] = vzero;

    // prologue: tile0 both kk + tile1 kk0; guarantee tile0 (tile1-kk0's 3 loads may fly)
    stageA(0, 0, 0); stageB(0, 0, 0);
    stageA(0, 0, 1); stageB(0, 0, 1);
    if (NT > 1) {
        stageA(1, 1, 0); stageB(1, 1, 0);
        asm volatile("s_waitcnt vmcnt(3)" ::: "memory");
    } else {
        asm volatile("s_waitcnt vmcnt(0)" ::: "memory");
    }
    __builtin_amdgcn_s_barrier();

    bf16x8 af[4], bfr[4];
#define GMM_MFMA16() do { \
    __builtin_amdgcn_s_setprio(1); \
    _Pragma("unroll") \
    for (int i_ = 0; i_ < 4; ++i_) { \
        _Pragma("unroll") \
        for (int j_ = 0; j_ < 4; ++j_) \
            acc[i_][j_] = __builtin_amdgcn_mfma_f32_16x16x32_bf16(af[i_], bfr[j_], acc[i_][j_], 0, 0, 0); \
    } \
    __builtin_amdgcn_s_setprio(0); \
    __builtin_amdgcn_s_barrier(); \
} while (0)

#pragma unroll 1
    for (int t = 0; t < NT; ++t) {
        const int buf = t & 1;
        const bf16* As0 = smem + buf * 16384;
        const bf16* As1 = As0 + 8192;
        const bf16* Bs0 = smem + 32768 + buf * 8192;
        const bf16* Bs1 = Bs0 + 4096;

        // phase A: kk0  (stage kk1(t+1) into other buf; its last read was tile t-1 phase B)
#pragma unroll
        for (int i = 0; i < 4; ++i) af[i]  = *(const bf16x8*)&As0[aBase + i * 512];
#pragma unroll
        for (int j = 0; j < 4; ++j) bfr[j] = *(const bf16x8*)&Bs0[bBase + j * 512];
        if (t + 1 < NT) { stageA(buf ^ 1, t + 1, 1); stageB(buf ^ 1, t + 1, 1); }
        PH_WAIT();
        GMM_MFMA16();

        // phase B: kk1  (stage kk0(t+2) into CURRENT buf: kk0 reads drained at phase-A barrier)
#pragma unroll
        for (int i = 0; i < 4; ++i) af[i]  = *(const bf16x8*)&As1[aBase + i * 512];
#pragma unroll
        for (int j = 0; j < 4; ++j) bfr[j] = *(const bf16x8*)&Bs1[bBase + j * 512];
        if (t + 2 < NT) {
            stageA(buf, t + 2, 0); stageB(buf, t + 2, 0);
            asm volatile("s_waitcnt vmcnt(3)" ::: "memory");
        } else {
            asm volatile("s_waitcnt vmcnt(0)" ::: "memory");
        }
        PH_WAIT();
        GMM_MFMA16();
    }
#undef GMM_MFMA16

    // epilogue
#pragma unroll
    for (int mf = 0; mf < 4; ++mf) {
#pragma unroll
        for (int nf = 0; nf < 4; ++nf) {
            const int col = n0 + wcn * 64 + nf * 16 + l16;
            float bcol, sc = 1.0f;
            if (EPI == 0) {
                const int seg = col >> 10;
                const float* bp = (seg == 0) ? bias : ((seg == 1) ? bias2 : bias3);
                bcol = bp[col & 1023];
                if (seg == 0) sc = QSCALE;
            } else {
                bcol = bias[col];
            }
#pragma unroll
            for (int r = 0; r < 4; ++r) {
                const int row = m0 + wr * 64 + mf * 16 + quad * 4 + r;
                const float v = acc[mf][nf][r] + bcol;
                if (EPI == 0) {
                    const int bb = row >> 11, ss = row & (SEQ - 1);
                    const int hh = (col & 1023) >> 6, dd = col & (DK - 1);
                    const size_t seg = (size_t)(col >> 10);
                    ((bf16*)outp)[seg * 8388608 + (((size_t)(bb * NHEADS + hh)) * SEQ + ss) * DK + dd] = (bf16)(v * sc);
                } else if (EPI == 1) {
                    const size_t idx = (size_t)row * N + col;
                    ((float*)outp)[idx] = v + resid[idx];
                } else {
                    ((bf16*)outp)[(size_t)row * N + col] = (bf16)fmaxf(v, 0.f);
                }
            }
        }
    }
}

// ---------------------------------------------------------------- flash attention (causal), S^T layout
__global__ __launch_bounds__(256, 2) void attn_kernel(
    const bf16* __restrict__ Q, const bf16* __restrict__ K,
    const bf16* __restrict__ VT, bf16* __restrict__ out)
{
    const int bh = blockIdx.x;
    const int b = bh >> 4, h = bh & 15;
    const int tid  = threadIdx.x;
    const int wave = tid >> 6, lane = tid & 63;
    const int quad = lane >> 4, l16 = lane & 15;

    __shared__ __align__(16) bf16 smem[32768 + 4 * 1152];
    bf16* Pw = smem + 32768 + wave * 1152;

    const bf16* Qb = Q  + (size_t)bh * SEQ * DK;
    const bf16* Kb = K  + (size_t)bh * SEQ * DK;
    const bf16* Vb = VT + (size_t)bh * DK * SEQ;

    int goK[4], goV[4], lo[4];
#pragma unroll
    for (int i = 0; i < 4; ++i) {
        const int U = (wave * 4 + i) * 64 + lane;
        const int rK = U >> 3, uK = (U & 7) ^ (rK & 7);
        goK[i] = rK * DK + uK * 8;
        const int rV = U >> 4, usw = U & 15;
        const int uV = (usw & 8) | ((usw & 7) ^ (rV & 7));
        goV[i] = rV * SEQ + uV * 8;
        lo[i]  = (wave * 4 + i) * 512;
    }

    auto stage = [&](int buf, int t) {
        const bf16* kp = Kb + (size_t)(t * 128) * DK;
        const bf16* vp = Vb + t * 128;
        bf16* kb = smem + buf * 8192;
        bf16* vb = smem + 16384 + buf * 8192;
#pragma unroll
        for (int i = 0; i < 4; ++i) gload16(kp + goK[i], kb + lo[i]);
#pragma unroll
        for (int i = 0; i < 4; ++i) gload16(vp + goV[i], vb + lo[i]);
    };

    const f32x4 vzero = {0.f, 0.f, 0.f, 0.f};
    int g = 0;
    stage(0, 0);

    for (int phase = 0; phase < 2; ++phase) {
        const int qt = phase ? (int)blockIdx.y : 15 - (int)blockIdx.y;
        const int qw = qt * 128 + wave * 32;

        bf16x8 qf[2][2];
#pragma unroll
        for (int qi = 0; qi < 2; ++qi)
#pragma unroll
            for (int kk = 0; kk < 2; ++kk)
                qf[qi][kk] = *(const bf16x8*)&Qb[(size_t)(qw + qi*16 + l16) * DK + kk*32 + quad*8];

        f32x4 Oacc[2][4];
        float m_[2], l_[2];
#pragma unroll
        for (int qi = 0; qi < 2; ++qi) {
            m_[qi] = -1.0e30f; l_[qi] = 0.f;
#pragma unroll
            for (int dj = 0; dj < 4; ++dj) Oacc[qi][dj] = vzero;
        }

        for (int t = 0; t <= qt; ++t, ++g) {
            const int cur = g & 1;
            __syncthreads();
            if (t < qt)            stage(cur ^ 1, t + 1);
            else if (phase == 0)   stage(cur ^ 1, 0);
            const bf16* kb = smem + cur * 8192;
            const bf16* vb = smem + 16384 + cur * 8192;
            const int kv0 = t * 128;

            f32x4 sv[8][2];
#pragma unroll
            for (int kvt = 0; kvt < 8; ++kvt) {
                const int R = kvt*16 + l16, rx = R & 7;
                bf16x8 kf0 = *(const bf16x8*)&kb[R*64 + (quad ^ rx)*8];
                bf16x8 kf1 = *(const bf16x8*)&kb[R*64 + (((quad + 4) & 7) ^ rx)*8];
#pragma unroll
                for (int qi = 0; qi < 2; ++qi) {
                    f32x4 tacc = vzero;
                    tacc = __builtin_amdgcn_mfma_f32_16x16x32_bf16(kf0, qf[qi][0], tacc, 0, 0, 0);
                    tacc = __builtin_amdgcn_mfma_f32_16x16x32_bf16(kf1, qf[qi][1], tacc, 0, 0, 0);
                    sv[kvt][qi] = tacc;
                }
            }

            if (t == qt) {
#pragma unroll
                for (int kvt = 0; kvt < 8; ++kvt)
#pragma unroll
                    for (int qi = 0; qi < 2; ++qi)
#pragma unroll
                        for (int r = 0; r < 4; ++r) {
                            const int kv = kv0 + kvt*16 + quad*4 + r;
                            const int q  = qw + qi*16 + l16;
                            if (kv > q) sv[kvt][qi][r] = -1.0e30f;
                        }
            }

#pragma unroll
            for (int qi = 0; qi < 2; ++qi) {
                float mx = sv[0][qi][0];
#pragma unroll
                for (int kvt = 0; kvt < 8; ++kvt)
#pragma unroll
                    for (int r = 0; r < 4; ++r) mx = fmaxf(mx, sv[kvt][qi][r]);
                mx = fmaxf(mx, __shfl_xor(mx, 16, 64));
                mx = fmaxf(mx, __shfl_xor(mx, 32, 64));
                const float newm  = fmaxf(m_[qi], mx);
                const float alpha = exp2f(m_[qi] - newm);
                m_[qi] = newm;
                float rs = 0.f;
#pragma unroll
                for (int kvt = 0; kvt < 8; ++kvt)
#pragma unroll
                    for (int r = 0; r < 4; ++r) {
                        const float p = exp2f(sv[kvt][qi][r] - newm);
                        sv[kvt][qi][r] = p;
                        rs += p;
                    }
                rs += __shfl_xor(rs, 16, 64);
                rs += __shfl_xor(rs, 32, 64);
                l_[qi] = l_[qi] * alpha + rs;
#pragma unroll
                for (int dj = 0; dj < 4; ++dj) Oacc[qi][dj] *= alpha;
            }

#pragma unroll
            for (int c2 = 0; c2 < 4; ++c2) {
#pragma unroll
                for (int qi = 0; qi < 2; ++qi)
#pragma unroll
                    for (int kl = 0; kl < 2; ++kl) {
                        union { bf16 h[4]; unsigned long long u; } pk;
                        const f32x4 s = sv[c2*2 + kl][qi];
#pragma unroll
                        for (int r = 0; r < 4; ++r) pk.h[r] = (bf16)s[r];
                        *(unsigned long long*)&Pw[(qi*16 + l16)*36 + kl*16 + quad*4] = pk.u;
                    }
                bf16x8 vf[4];
#pragma unroll
                for (int dj = 0; dj < 4; ++dj) {
                    const int R = dj*16 + l16;
                    const int u = c2*4 + quad;
                    const int usw = (u & 8) | ((u & 7) ^ (R & 7));
                    vf[dj] = *(const bf16x8*)&vb[R*128 + usw*8];
                }
#pragma unroll
                for (int qi = 0; qi < 2; ++qi) {
                    bf16x8 pf = *(const bf16x8*)&Pw[(qi*16 + l16)*36 + quad*8];
#pragma unroll
                    for (int dj = 0; dj < 4; ++dj)
                        Oacc[qi][dj] = __builtin_amdgcn_mfma_f32_16x16x32_bf16(vf[dj], pf, Oacc[qi][dj], 0, 0, 0);
                }
            }
        }

        const float inv0 = 1.0f / l_[0], inv1 = 1.0f / l_[1];
#pragma unroll
        for (int dh = 0; dh < 2; ++dh) {
#pragma unroll
            for (int qi = 0; qi < 2; ++qi) {
                const float inv = qi ? inv1 : inv0;
#pragma unroll
                for (int djl = 0; djl < 2; ++djl) {
                    const int dj = dh*2 + djl;
                    union { bf16 h[4]; unsigned long long u; } ok;
#pragma unroll
                    for (int r = 0; r < 4; ++r) ok.h[r] = (bf16)(Oacc[qi][dj][r] * inv);
                    *(unsigned long long*)&Pw[(qi*16 + l16)*36 + djl*16 + quad*4] = ok.u;
                }
            }
            const int row = lane >> 1;
#pragma unroll
            for (int it = 0; it < 2; ++it) {
                const int grp = (lane & 1) + 2*it;
                bf16x8 o = *(const bf16x8*)&Pw[row*36 + grp*8];
                *(bf16x8*)&out[((size_t)(b*SEQ + qw - wave*32 + wave*32 + row))*D_MODEL + h*DK + dh*32 + grp*8] = o;
            }
        }
    }
}

// ---------------------------------------------------------------- launch
extern "C" void kernel_launch(void* const* d_in, const int* in_sizes, int n_in,
                              void* d_out, int out_size, void* d_ws, size_t ws_size,
                              hipStream_t stream)
{
    const float* x    = (const float*)d_in[0];
    const float* Wq   = (const float*)d_in[1];
    const float* bq   = (const float*)d_in[2];
    const float* Wk   = (const float*)d_in[3];
    const float* bk   = (const float*)d_in[4];
    const float* Wv   = (const float*)d_in[5];
    const float* bv   = (const float*)d_in[6];
    const float* Wo   = (const float*)d_in[7];
    const float* bo   = (const float*)d_in[8];
    const float* W1   = (const float*)d_in[9];
    const float* b1   = (const float*)d_in[10];
    const float* W2   = (const float*)d_in[11];
    const float* b2   = (const float*)d_in[12];
    const float* ln1g = (const float*)d_in[13];
    const float* ln1b = (const float*)d_in[14];
    const float* ln2g = (const float*)d_in[15];
    const float* ln2b = (const float*)d_in[16];

    char* ws = (char*)d_ws;
    const size_t MB = 1024 * 1024;
    bf16* WTq  = (bf16*)(ws + 0 * MB);
    bf16* WTk  = (bf16*)(ws + 2 * MB);
    bf16* WTv  = (bf16*)(ws + 4 * MB);
    bf16* WTo  = (bf16*)(ws + 6 * MB);
    bf16* WT1  = (bf16*)(ws + 8 * MB);
    bf16* WT2  = (bf16*)(ws + 16 * MB);
    bf16* hbuf = (bf16*)(ws + 24 * MB);
    bf16* VhT  = (bf16*)(ws + 24 * MB);
    bf16* Qh   = (bf16*)(ws + 40 * MB);
    bf16* Kh   = (bf16*)(ws + 56 * MB);
    bf16* Vh   = (bf16*)(ws + 72 * MB);
    bf16* attn = (bf16*)(ws + 88 * MB);
    bf16* ff1  = (bf16*)(ws + 40 * MB);
    float* x2  = (float*)d_out;

    dim3 tb(32, 8);
    transpose_cast4<<<dim3(32, 32, 4), tb, 0, stream>>>(Wq, Wk, Wv, Wo, WTq, WTk, WTv, WTo);
    transpose_cast<<<dim3(128, 32), tb, 0, stream>>>(W1, WT1, 1024, 4096);
    transpose_cast<<<dim3(32, 128), tb, 0, stream>>>(W2, WT2, 4096, 1024);

    ln_kernel<<<NTOK, 256, 0, stream>>>(x, ln1g, ln1b, hbuf);

    // fused QKV: 256x128 tile -> 32x24 = 768 blocks = 3 full occupancy rounds
    gemm256n128<0><<<dim3(32, 24), 512, 0, stream>>>(hbuf, WTq, bq, bk, bv, nullptr, Qh, NTOK, 3072, 1024);

    transpose_v<<<dim3(32, 64), 256, 0, stream>>>(Vh, VhT);

    attn_kernel<<<dim3(64, 8), 256, 0, stream>>>(Qh, Kh, VhT, attn);

    // O-proj: 256x128 -> 256 blocks = full GPU
    gemm256n128<1><<<dim3(32, 8), 512, 0, stream>>>(attn, WTo, bo, nullptr, nullptr, x, x2, NTOK, 1024, 1024);

    ln_kernel<<<NTOK, 256, 0, stream>>>(x2, ln2g, ln2b, hbuf);

    // FF1: 256^2 8-phase, 512 blocks = 2 full occupancy rounds
    gemm256<2><<<dim3(32, 16), 512, 0, stream>>>(hbuf, WT1, b1, nullptr, nullptr, nullptr, ff1, NTOK, 4096, 1024);
    // FF2: 256x128 -> 256 blocks = full GPU, K=4096 deep pipeline
    gemm256n128<1><<<dim3(32, 8), 512, 0, stream>>>(ff1, WT2, b2, nullptr, nullptr, x2, x2, NTOK, 1024, 4096);
}

// Round 3
// 489.905 us; speedup vs baseline: 1.0749x; 1.0206x over previous
//
#include <hip/hip_runtime.h>
#include <hip/hip_bf16.h>

typedef __bf16 bf16;
typedef __attribute__((ext_vector_type(8))) __bf16 bf16x8;
typedef __attribute__((ext_vector_type(4))) float f32x4;

#define D_MODEL 1024
#define NHEADS  16
#define DK      64
#define DFF     4096
#define BATCH   4
#define SEQ     2048
#define NTOK    (BATCH*SEQ)   // 8192
#define QSCALE  0.18033688011112042f   // 0.125 * log2(e)

__device__ __forceinline__ void gload16(const bf16* g, bf16* l) {
    __builtin_amdgcn_global_load_lds((const __attribute__((address_space(1))) void*)g,
                                     (__attribute__((address_space(3))) void*)l, 16, 0, 0);
}

// ---------------------------------------------------------------- transpose+cast (4x 1024^2 fused on z)
__global__ __launch_bounds__(256) void transpose_cast4(
    const float* __restrict__ W0, const float* __restrict__ W1,
    const float* __restrict__ W2, const float* __restrict__ W3,
    bf16* __restrict__ T0, bf16* __restrict__ T1,
    bf16* __restrict__ T2, bf16* __restrict__ T3)
{
    const int z = blockIdx.z;
    const float* W = (z == 0) ? W0 : (z == 1) ? W1 : (z == 2) ? W2 : W3;
    bf16*       Wt = (z == 0) ? T0 : (z == 1) ? T1 : (z == 2) ? T2 : T3;
    const int K = 1024, N = 1024;
    __shared__ float tile[32][33];
    const int tx = threadIdx.x, ty = threadIdx.y;
    const int n0 = blockIdx.x * 32, k0 = blockIdx.y * 32;
#pragma unroll
    for (int i = 0; i < 4; ++i)
        tile[ty + i*8][tx] = W[(size_t)(k0 + ty + i*8) * N + n0 + tx];
    __syncthreads();
#pragma unroll
    for (int i = 0; i < 4; ++i)
        Wt[(size_t)(n0 + ty + i*8) * K + k0 + tx] = (bf16)tile[tx][ty + i*8];
}

__global__ __launch_bounds__(256) void transpose_cast(
    const float* __restrict__ W, bf16* __restrict__ Wt, int K, int N)
{
    __shared__ float tile[32][33];
    const int tx = threadIdx.x, ty = threadIdx.y;
    const int n0 = blockIdx.x * 32, k0 = blockIdx.y * 32;
#pragma unroll
    for (int i = 0; i < 4; ++i)
        tile[ty + i*8][tx] = W[(size_t)(k0 + ty + i*8) * N + n0 + tx];
    __syncthreads();
#pragma unroll
    for (int i = 0; i < 4; ++i)
        Wt[(size_t)(n0 + ty + i*8) * K + k0 + tx] = (bf16)tile[tx][ty + i*8];
}

// ---------------------------------------------------------------- V head-transpose
// Vh[bh][s][64] -> VhT[bh][64][2048]
__global__ __launch_bounds__(256) void transpose_v(
    const bf16* __restrict__ V, bf16* __restrict__ VT)
{
    __shared__ bf16 t[64][72];
    const int bh = blockIdx.y;
    const int s0 = blockIdx.x * 64;
    const int r  = threadIdx.x >> 2;         // 0..63
    const int c0 = (threadIdx.x & 3) * 16;   // 0,16,32,48
    const bf16* Vb = V  + (size_t)bh * SEQ * DK;
    bf16*       Tb = VT + (size_t)bh * DK * SEQ;
#pragma unroll
    for (int i = 0; i < 2; ++i) {
        bf16x8 v = *(const bf16x8*)&Vb[(size_t)(s0 + r) * DK + c0 + i*8];
#pragma unroll
        for (int j = 0; j < 8; ++j) t[c0 + i*8 + j][r] = v[j];
    }
    __syncthreads();
#pragma unroll
    for (int i = 0; i < 2; ++i) {
        bf16x8 o;
#pragma unroll
        for (int j = 0; j < 8; ++j) o[j] = t[r][c0 + i*8 + j];
        *(bf16x8*)&Tb[(size_t)r * SEQ + s0 + c0 + i*8] = o;
    }
}

// ---------------------------------------------------------------- layernorm (fp32 in, bf16 out)
__global__ __launch_bounds__(256) void ln_kernel(
    const float* __restrict__ x, const float* __restrict__ g,
    const float* __restrict__ beta, bf16* __restrict__ out)
{
    const int row = blockIdx.x, tid = threadIdx.x;
    const f32x4* xr = (const f32x4*)(x + (size_t)row * D_MODEL);
    f32x4 v = xr[tid];
    float s  = v[0] + v[1] + v[2] + v[3];
    float s2 = v[0]*v[0] + v[1]*v[1] + v[2]*v[2] + v[3]*v[3];
#pragma unroll
    for (int off = 32; off > 0; off >>= 1) {
        s  += __shfl_down(s,  off, 64);
        s2 += __shfl_down(s2, off, 64);
    }
    __shared__ float red[8];
    const int wave = tid >> 6, lane = tid & 63;
    if (lane == 0) { red[wave] = s; red[wave + 4] = s2; }
    __syncthreads();
    if (tid == 0) {
        float a = red[0] + red[1] + red[2] + red[3];
        float c = red[4] + red[5] + red[6] + red[7];
        float mu  = a * (1.0f / D_MODEL);
        float var = c * (1.0f / D_MODEL) - mu * mu;
        red[0] = mu;
        red[1] = rsqrtf(var + 1e-5f);
    }
    __syncthreads();
    const float mu = red[0], rs = red[1];
    f32x4 gv = ((const f32x4*)g)[tid];
    f32x4 bv = ((const f32x4*)beta)[tid];
    union { bf16 h[4]; uint2 u; } o;
#pragma unroll
    for (int i = 0; i < 4; ++i) o.h[i] = (bf16)((v[i] - mu) * rs * gv[i] + bv[i]);
    *(uint2*)(out + (size_t)row * D_MODEL + tid * 4) = o.u;
}

#define PH_WAIT() do { \
    __builtin_amdgcn_s_barrier(); \
    asm volatile("s_waitcnt lgkmcnt(0)" ::: "memory"); \
    __builtin_amdgcn_sched_barrier(0); \
} while (0)

// ---------------------------------------------------------------- bf16 GEMM, 256x256 tile, BK=64, 8-wave 8-phase
// (used where gridDim is a multiple of 256 blocks: FF1)
template<int EPI>
__global__ __launch_bounds__(512, 2) void gemm256(
    const bf16* __restrict__ A, const bf16* __restrict__ Bt,
    const float* __restrict__ bias, const float* __restrict__ bias2,
    const float* __restrict__ bias3, const float* __restrict__ resid,
    void* __restrict__ outp, int M, int N, int K)
{
    __shared__ __align__(16) bf16 smem[65536];   // 128 KiB
    const int tid  = threadIdx.x;
    const int wave = tid >> 6, lane = tid & 63;
    const int quad = lane >> 4, l16 = lane & 15;
    const int wr = wave >> 2, wcn = wave & 3;    // 2 x 4 wave grid; per-wave C = 128x64
    const int m0 = blockIdx.x * 256, n0 = blockIdx.y * 256;
    const int NT = K >> 6;

    const bf16* gA[2]; const bf16* gB[2]; int ldsOff[2];
#pragma unroll
    for (int l = 0; l < 2; ++l) {
        const int slot = tid + l * 512;
        const int r = slot >> 2;
        const int clog = (slot & 3) ^ ((r >> 1) & 3);
        gA[l] = A  + (size_t)(m0 + r) * K + clog * 8;
        gB[l] = Bt + (size_t)(n0 + r) * K + clog * 8;
        ldsOff[l] = (wave * 64 + l * 512) * 8;
    }

    auto stageA = [&](int buf, int t, int kk) {
        bf16* dst = smem + (buf * 2 + kk) * 8192;
#pragma unroll
        for (int l = 0; l < 2; ++l) gload16(gA[l] + t * 64 + kk * 32, dst + ldsOff[l]);
    };
    auto stageB = [&](int buf, int t, int kk) {
        bf16* dst = smem + 32768 + (buf * 2 + kk) * 8192;
#pragma unroll
        for (int l = 0; l < 2; ++l) gload16(gB[l] + t * 64 + kk * 32, dst + ldsOff[l]);
    };

    const int cswz  = (quad ^ ((l16 >> 1) & 3)) * 8;
    const int aBase = (wr * 128 + l16) * 32 + cswz;
    const int bBase = (wcn * 64 + l16) * 32 + cswz;

    f32x4 acc[8][4];
    const f32x4 vzero = {0.f, 0.f, 0.f, 0.f};
#pragma unroll
    for (int i = 0; i < 8; ++i)
#pragma unroll
        for (int j = 0; j < 4; ++j) acc[i][j] = vzero;

    stageA(0, 0, 0); stageB(0, 0, 0);
    stageA(0, 0, 1); stageB(0, 0, 1);
    if (NT > 1) {
        stageA(1, 1, 0); stageB(1, 1, 0);
        asm volatile("s_waitcnt vmcnt(4)" ::: "memory");
    } else {
        asm volatile("s_waitcnt vmcnt(0)" ::: "memory");
    }
    __builtin_amdgcn_s_barrier();

    bf16x8 af[4], bfr[4];
#define GMM_MFMA(mh) do { \
    __builtin_amdgcn_s_setprio(1); \
    _Pragma("unroll") \
    for (int i_ = 0; i_ < 4; ++i_) { \
        _Pragma("unroll") \
        for (int j_ = 0; j_ < 4; ++j_) \
            acc[(mh)*4 + i_][j_] = __builtin_amdgcn_mfma_f32_16x16x32_bf16(af[i_], bfr[j_], acc[(mh)*4 + i_][j_], 0, 0, 0); \
    } \
    __builtin_amdgcn_s_setprio(0); \
    __builtin_amdgcn_s_barrier(); \
} while (0)

#pragma unroll 1
    for (int t = 0; t < NT; ++t) {
        const int buf = t & 1;
        const bf16* As0 = smem + buf * 16384;
        const bf16* As1 = As0 + 8192;
        const bf16* Bs0 = smem + 32768 + buf * 16384;
        const bf16* Bs1 = Bs0 + 8192;

#pragma unroll
        for (int i = 0; i < 4; ++i) af[i]  = *(const bf16x8*)&As0[aBase + i * 512];
#pragma unroll
        for (int j = 0; j < 4; ++j) bfr[j] = *(const bf16x8*)&Bs0[bBase + j * 512];
        if (t + 1 < NT) stageA(buf ^ 1, t + 1, 1);
        PH_WAIT();
        GMM_MFMA(0);

#pragma unroll
        for (int i = 0; i < 4; ++i) af[i] = *(const bf16x8*)&As0[aBase + 2048 + i * 512];
        if (t + 1 < NT) stageB(buf ^ 1, t + 1, 1);
        PH_WAIT();
        GMM_MFMA(1);

#pragma unroll
        for (int i = 0; i < 4; ++i) af[i]  = *(const bf16x8*)&As1[aBase + 2048 + i * 512];
#pragma unroll
        for (int j = 0; j < 4; ++j) bfr[j] = *(const bf16x8*)&Bs1[bBase + j * 512];
        if (t + 2 < NT) stageA(buf, t + 2, 0);
        PH_WAIT();
        GMM_MFMA(1);

#pragma unroll
        for (int i = 0; i < 4; ++i) af[i] = *(const bf16x8*)&As1[aBase + i * 512];
        if (t + 2 < NT) {
            stageB(buf, t + 2, 0);
            asm volatile("s_waitcnt vmcnt(4)" ::: "memory");
        } else {
            asm volatile("s_waitcnt vmcnt(0)" ::: "memory");
        }
        PH_WAIT();
        GMM_MFMA(0);
    }
#undef GMM_MFMA

#pragma unroll
    for (int mf = 0; mf < 8; ++mf) {
#pragma unroll
        for (int nf = 0; nf < 4; ++nf) {
            const int col = n0 + wcn * 64 + nf * 16 + l16;
            float bcol, sc = 1.0f;
            if (EPI == 0) {
                const int seg = col >> 10;
                const float* bp = (seg == 0) ? bias : ((seg == 1) ? bias2 : bias3);
                bcol = bp[col & 1023];
                if (seg == 0) sc = QSCALE;
            } else {
                bcol = bias[col];
            }
#pragma unroll
            for (int r = 0; r < 4; ++r) {
                const int row = m0 + wr * 128 + mf * 16 + quad * 4 + r;
                const float v = acc[mf][nf][r] + bcol;
                if (EPI == 0) {
                    const int bb = row >> 11, ss = row & (SEQ - 1);
                    const int hh = (col & 1023) >> 6, dd = col & (DK - 1);
                    const size_t seg = (size_t)(col >> 10);
                    ((bf16*)outp)[seg * 8388608 + (((size_t)(bb * NHEADS + hh)) * SEQ + ss) * DK + dd] = (bf16)(v * sc);
                } else if (EPI == 1) {
                    const size_t idx = (size_t)row * N + col;
                    ((float*)outp)[idx] = v + resid[idx];
                } else {
                    ((bf16*)outp)[(size_t)row * N + col] = (bf16)fmaxf(v, 0.f);
                }
            }
        }
    }
}

// ---------------------------------------------------------------- bf16 GEMM, 256x128 tile, BK=64, 8-wave, 2 phases/K-tile
template<int EPI>
__global__ __launch_bounds__(512, 2) void gemm256n128(
    const bf16* __restrict__ A, const bf16* __restrict__ Bt,
    const float* __restrict__ bias, const float* __restrict__ bias2,
    const float* __restrict__ bias3, const float* __restrict__ resid,
    void* __restrict__ outp, int M, int N, int K)
{
    __shared__ __align__(16) bf16 smem[49152];   // 96 KiB
    const int tid  = threadIdx.x;
    const int wave = tid >> 6, lane = tid & 63;
    const int quad = lane >> 4, l16 = lane & 15;
    const int wr = wave >> 1, wcn = wave & 1;    // 4 x 2 wave grid; per-wave C = 64x64
    const int m0 = blockIdx.x * 256, n0 = blockIdx.y * 128;
    const int NT = K >> 6;

    const bf16* gA[2]; const bf16* gB0; int ldsOffA[2];
#pragma unroll
    for (int l = 0; l < 2; ++l) {
        const int slot = tid + l * 512;
        const int r = slot >> 2;
        const int clog = (slot & 3) ^ ((r >> 1) & 3);
        gA[l] = A + (size_t)(m0 + r) * K + clog * 8;
        ldsOffA[l] = (wave * 64 + l * 512) * 8;
    }
    {
        const int r = tid >> 2;
        const int clog = (tid & 3) ^ ((r >> 1) & 3);
        gB0 = Bt + (size_t)(n0 + r) * K + clog * 8;
    }
    const int ldsOffB = wave * 512;

    auto stageA = [&](int buf, int t, int kk) {
        bf16* dst = smem + (buf * 2 + kk) * 8192;
#pragma unroll
        for (int l = 0; l < 2; ++l) gload16(gA[l] + t * 64 + kk * 32, dst + ldsOffA[l]);
    };
    auto stageB = [&](int buf, int t, int kk) {
        bf16* dst = smem + 32768 + (buf * 2 + kk) * 4096;
        gload16(gB0 + t * 64 + kk * 32, dst + ldsOffB);
    };

    const int cswz  = (quad ^ ((l16 >> 1) & 3)) * 8;
    const int aBase = (wr * 64 + l16) * 32 + cswz;
    const int bBase = (wcn * 64 + l16) * 32 + cswz;

    f32x4 acc[4][4];
    const f32x4 vzero = {0.f, 0.f, 0.f, 0.f};
#pragma unroll
    for (int i = 0; i < 4; ++i)
#pragma unroll
        for (int j = 0; j < 4; ++j) acc[i][j] = vzero;

    stageA(0, 0, 0); stageB(0, 0, 0);
    stageA(0, 0, 1); stageB(0, 0, 1);
    if (NT > 1) {
        stageA(1, 1, 0); stageB(1, 1, 0);
        asm volatile("s_waitcnt vmcnt(3)" ::: "memory");
    } else {
        asm volatile("s_waitcnt vmcnt(0)" ::: "memory");
    }
    __builtin_amdgcn_s_barrier();

    bf16x8 af[4], bfr[4];
#define GMM_MFMA16() do { \
    __builtin_amdgcn_s_setprio(1); \
    _Pragma("unroll") \
    for (int i_ = 0; i_ < 4; ++i_) { \
        _Pragma("unroll") \
        for (int j_ = 0; j_ < 4; ++j_) \
            acc[i_][j_] = __builtin_amdgcn_mfma_f32_16x16x32_bf16(af[i_], bfr[j_], acc[i_][j_], 0, 0, 0); \
    } \
    __builtin_amdgcn_s_setprio(0); \
    __builtin_amdgcn_s_barrier(); \
} while (0)

#pragma unroll 1
    for (int t = 0; t < NT; ++t) {
        const int buf = t & 1;
        const bf16* As0 = smem + buf * 16384;
        const bf16* As1 = As0 + 8192;
        const bf16* Bs0 = smem + 32768 + buf * 8192;
        const bf16* Bs1 = Bs0 + 4096;

#pragma unroll
        for (int i = 0; i < 4; ++i) af[i]  = *(const bf16x8*)&As0[aBase + i * 512];
#pragma unroll
        for (int j = 0; j < 4; ++j) bfr[j] = *(const bf16x8*)&Bs0[bBase + j * 512];
        if (t + 1 < NT) { stageA(buf ^ 1, t + 1, 1); stageB(buf ^ 1, t + 1, 1); }
        PH_WAIT();
        GMM_MFMA16();

#pragma unroll
        for (int i = 0; i < 4; ++i) af[i]  = *(const bf16x8*)&As1[aBase + i * 512];
#pragma unroll
        for (int j = 0; j < 4; ++j) bfr[j] = *(const bf16x8*)&Bs1[bBase + j * 512];
        if (t + 2 < NT) {
            stageA(buf, t + 2, 0); stageB(buf, t + 2, 0);
            asm volatile("s_waitcnt vmcnt(3)" ::: "memory");
        } else {
            asm volatile("s_waitcnt vmcnt(0)" ::: "memory");
        }
        PH_WAIT();
        GMM_MFMA16();
    }
#undef GMM_MFMA16

#pragma unroll
    for (int mf = 0; mf < 4; ++mf) {
#pragma unroll
        for (int nf = 0; nf < 4; ++nf) {
            const int col = n0 + wcn * 64 + nf * 16 + l16;
            float bcol, sc = 1.0f;
            if (EPI == 0) {
                const int seg = col >> 10;
                const float* bp = (seg == 0) ? bias : ((seg == 1) ? bias2 : bias3);
                bcol = bp[col & 1023];
                if (seg == 0) sc = QSCALE;
            } else {
                bcol = bias[col];
            }
#pragma unroll
            for (int r = 0; r < 4; ++r) {
                const int row = m0 + wr * 64 + mf * 16 + quad * 4 + r;
                const float v = acc[mf][nf][r] + bcol;
                if (EPI == 0) {
                    const int bb = row >> 11, ss = row & (SEQ - 1);
                    const int hh = (col & 1023) >> 6, dd = col & (DK - 1);
                    const size_t seg = (size_t)(col >> 10);
                    ((bf16*)outp)[seg * 8388608 + (((size_t)(bb * NHEADS + hh)) * SEQ + ss) * DK + dd] = (bf16)(v * sc);
                } else if (EPI == 1) {
                    const size_t idx = (size_t)row * N + col;
                    ((float*)outp)[idx] = v + resid[idx];
                } else {
                    ((bf16*)outp)[(size_t)row * N + col] = (bf16)fmaxf(v, 0.f);
                }
            }
        }
    }
}

// ---------------------------------------------------------------- flash attention (causal), S^T layout
// P relayout for PV is now fully in-register: cvt-pack pairs + v_permlane32_swap_b32 +
// xor-16 shuffle + quad-parity select (replaces the Pw LDS round-trip in the inner loop).
// Defer-max (T13, THR=8 in log2 units): skip m/l/Oacc rescale while tile max stays within 8.
__global__ __launch_bounds__(256, 2) void attn_kernel(
    const bf16* __restrict__ Q, const bf16* __restrict__ K,
    const bf16* __restrict__ VT, bf16* __restrict__ out)
{
    const int bh = blockIdx.x;
    const int b = bh >> 4, h = bh & 15;
    const int tid  = threadIdx.x;
    const int wave = tid >> 6, lane = tid & 63;
    const int quad = lane >> 4, l16 = lane & 15;

    __shared__ __align__(16) bf16 smem[32768 + 4 * 1152];
    bf16* Pw = smem + 32768 + wave * 1152;   // epilogue-only now

    const bf16* Qb = Q  + (size_t)bh * SEQ * DK;
    const bf16* Kb = K  + (size_t)bh * SEQ * DK;
    const bf16* Vb = VT + (size_t)bh * DK * SEQ;

    int goK[4], goV[4], lo[4];
#pragma unroll
    for (int i = 0; i < 4; ++i) {
        const int U = (wave * 4 + i) * 64 + lane;
        const int rK = U >> 3, uK = (U & 7) ^ (rK & 7);
        goK[i] = rK * DK + uK * 8;
        const int rV = U >> 4, usw = U & 15;
        const int uV = (usw & 8) | ((usw & 7) ^ (rV & 7));
        goV[i] = rV * SEQ + uV * 8;
        lo[i]  = (wave * 4 + i) * 512;
    }

    auto stage = [&](int buf, int t) {
        const bf16* kp = Kb + (size_t)(t * 128) * DK;
        const bf16* vp = Vb + t * 128;
        bf16* kb = smem + buf * 8192;
        bf16* vb = smem + 16384 + buf * 8192;
#pragma unroll
        for (int i = 0; i < 4; ++i) gload16(kp + goK[i], kb + lo[i]);
#pragma unroll
        for (int i = 0; i < 4; ++i) gload16(vp + goV[i], vb + lo[i]);
    };

    const f32x4 vzero = {0.f, 0.f, 0.f, 0.f};
    int g = 0;
    stage(0, 0);

    for (int phase = 0; phase < 2; ++phase) {
        const int qt = phase ? (int)blockIdx.y : 15 - (int)blockIdx.y;
        const int qw = qt * 128 + wave * 32;

        bf16x8 qf[2][2];
#pragma unroll
        for (int qi = 0; qi < 2; ++qi)
#pragma unroll
            for (int kk = 0; kk < 2; ++kk)
                qf[qi][kk] = *(const bf16x8*)&Qb[(size_t)(qw + qi*16 + l16) * DK + kk*32 + quad*8];

        f32x4 Oacc[2][4];
        float m_[2], l_[2];
#pragma unroll
        for (int qi = 0; qi < 2; ++qi) {
            m_[qi] = -1.0e30f; l_[qi] = 0.f;
#pragma unroll
            for (int dj = 0; dj < 4; ++dj) Oacc[qi][dj] = vzero;
        }

        for (int t = 0; t <= qt; ++t, ++g) {
            const int cur = g & 1;
            __syncthreads();
            if (t < qt)            stage(cur ^ 1, t + 1);
            else if (phase == 0)   stage(cur ^ 1, 0);
            const bf16* kb = smem + cur * 8192;
            const bf16* vb = smem + 16384 + cur * 8192;
            const int kv0 = t * 128;

            f32x4 sv[8][2];
#pragma unroll
            for (int kvt = 0; kvt < 8; ++kvt) {
                const int R = kvt*16 + l16, rx = R & 7;
                bf16x8 kf0 = *(const bf16x8*)&kb[R*64 + (quad ^ rx)*8];
                bf16x8 kf1 = *(const bf16x8*)&kb[R*64 + (((quad + 4) & 7) ^ rx)*8];
#pragma unroll
                for (int qi = 0; qi < 2; ++qi) {
                    f32x4 tacc = vzero;
                    tacc = __builtin_amdgcn_mfma_f32_16x16x32_bf16(kf0, qf[qi][0], tacc, 0, 0, 0);
                    tacc = __builtin_amdgcn_mfma_f32_16x16x32_bf16(kf1, qf[qi][1], tacc, 0, 0, 0);
                    sv[kvt][qi] = tacc;
                }
            }

            if (t == qt) {   // diagonal: causal mask
#pragma unroll
                for (int kvt = 0; kvt < 8; ++kvt)
#pragma unroll
                    for (int qi = 0; qi < 2; ++qi)
#pragma unroll
                        for (int r = 0; r < 4; ++r) {
                            const int kv = kv0 + kvt*16 + quad*4 + r;
                            const int q  = qw + qi*16 + l16;
                            if (kv > q) sv[kvt][qi][r] = -1.0e30f;
                        }
            }

            // tile max per q-row (max3-friendly trees), quad-group reduce
            float mx[2];
#pragma unroll
            for (int qi = 0; qi < 2; ++qi) {
                float hx[8];
#pragma unroll
                for (int kvt = 0; kvt < 8; ++kvt)
                    hx[kvt] = fmaxf(fmaxf(fmaxf(sv[kvt][qi][0], sv[kvt][qi][1]), sv[kvt][qi][2]), sv[kvt][qi][3]);
                float m4 = fmaxf(fmaxf(fmaxf(hx[0], hx[1]), hx[2]), hx[3]);
                m4 = fmaxf(fmaxf(fmaxf(m4, hx[4]), fmaxf(hx[5], hx[6])), hx[7]);
                m4 = fmaxf(m4, __shfl_xor(m4, 16, 64));
                mx[qi] = fmaxf(m4, __shfl_xor(m4, 32, 64));
            }

            // defer-max: only rescale when the tile max exceeds running max by > 8 (log2)
            if (__any((mx[0] > m_[0] + 8.f) || (mx[1] > m_[1] + 8.f))) {
#pragma unroll
                for (int qi = 0; qi < 2; ++qi) {
                    const float newm  = fmaxf(m_[qi], mx[qi]);
                    const float alpha = exp2f(m_[qi] - newm);
                    m_[qi] = newm;
                    l_[qi] *= alpha;
#pragma unroll
                    for (int dj = 0; dj < 4; ++dj) Oacc[qi][dj] *= alpha;
                }
            }

            // exponentiate + row-sum (P bounded by 2^8)
#pragma unroll
            for (int qi = 0; qi < 2; ++qi) {
                float rs = 0.f;
#pragma unroll
                for (int kvt = 0; kvt < 8; ++kvt)
#pragma unroll
                    for (int r = 0; r < 4; ++r) {
                        const float p = exp2f(sv[kvt][qi][r] - m_[qi]);
                        sv[kvt][qi][r] = p;
                        rs += p;
                    }
                rs += __shfl_xor(rs, 16, 64);
                rs += __shfl_xor(rs, 32, 64);
                l_[qi] += rs;
            }

            // O^T += V^T·P^T in 32-kv chunks; P relayout fully in-register
#pragma unroll
            for (int c2 = 0; c2 < 4; ++c2) {
                bf16x8 vf[4];
#pragma unroll
                for (int dj = 0; dj < 4; ++dj) {
                    const int R = dj*16 + l16;
                    const int u = c2*4 + quad;
                    const int usw = (u & 8) | ((u & 7) ^ (R & 7));
                    vf[dj] = *(const bf16x8*)&vb[R*128 + usw*8];
                }
#pragma unroll
                for (int qi = 0; qi < 2; ++qi) {
                    const f32x4 A = sv[c2*2 + 0][qi];
                    const f32x4 B = sv[c2*2 + 1][qi];
                    union { bf16 h[2]; int u; } pA01, pA23, pB01, pB23;
                    pA01.h[0] = (bf16)A[0]; pA01.h[1] = (bf16)A[1];
                    pA23.h[0] = (bf16)A[2]; pA23.h[1] = (bf16)A[3];
                    pB01.h[0] = (bf16)B[0]; pB01.h[1] = (bf16)B[1];
                    pB23.h[0] = (bf16)B[2]; pB23.h[1] = (bf16)B[3];
                    int a01 = pA01.u, a23 = pA23.u, b01 = pB01.u, b23 = pB23.u;
                    // swap: a01 -> {A_low | B_low}, b01 -> {A_high | B_high}
                    asm volatile("v_permlane32_swap_b32 %0, %1" : "+v"(a01), "+v"(b01));
                    asm volatile("v_permlane32_swap_b32 %0, %1" : "+v"(a23), "+v"(b23));
                    const int x01 = __shfl_xor(b01, 16, 64);   // xor16 of high-half vector
                    const int x23 = __shfl_xor(b23, 16, 64);
                    const int y01 = __shfl_xor(a01, 16, 64);   // xor16 of low-half vector
                    const int y23 = __shfl_xor(a23, 16, 64);
                    const bool odd = (quad & 1) != 0;
                    union { int w[4]; bf16x8 v; } pf;
                    pf.w[0] = odd ? x01 : a01;
                    pf.w[1] = odd ? x23 : a23;
                    pf.w[2] = odd ? b01 : y01;
                    pf.w[3] = odd ? b23 : y23;
#pragma unroll
                    for (int dj = 0; dj < 4; ++dj)
                        Oacc[qi][dj] = __builtin_amdgcn_mfma_f32_16x16x32_bf16(vf[dj], pf.v, Oacc[qi][dj], 0, 0, 0);
                }
            }
        }

        // phase epilogue through private Pw (no barrier): chunked [32 q][32 d] halves
        const float inv0 = 1.0f / l_[0], inv1 = 1.0f / l_[1];
#pragma unroll
        for (int dh = 0; dh < 2; ++dh) {
#pragma unroll
            for (int qi = 0; qi < 2; ++qi) {
                const float inv = qi ? inv1 : inv0;
#pragma unroll
                for (int djl = 0; djl < 2; ++djl) {
                    const int dj = dh*2 + djl;
                    union { bf16 h[4]; unsigned long long u; } ok;
#pragma unroll
                    for (int r = 0; r < 4; ++r) ok.h[r] = (bf16)(Oacc[qi][dj][r] * inv);
                    *(unsigned long long*)&Pw[(qi*16 + l16)*36 + djl*16 + quad*4] = ok.u;
                }
            }
            const int row = lane >> 1;
#pragma unroll
            for (int it = 0; it < 2; ++it) {
                const int grp = (lane & 1) + 2*it;
                bf16x8 o = *(const bf16x8*)&Pw[row*36 + grp*8];
                *(bf16x8*)&out[((size_t)(b*SEQ + qw - wave*32 + wave*32 + row))*D_MODEL + h*DK + dh*32 + grp*8] = o;
            }
        }
    }
}

// ---------------------------------------------------------------- launch
extern "C" void kernel_launch(void* const* d_in, const int* in_sizes, int n_in,
                              void* d_out, int out_size, void* d_ws, size_t ws_size,
                              hipStream_t stream)
{
    const float* x    = (const float*)d_in[0];
    const float* Wq   = (const float*)d_in[1];
    const float* bq   = (const float*)d_in[2];
    const float* Wk   = (const float*)d_in[3];
    const float* bk   = (const float*)d_in[4];
    const float* Wv   = (const float*)d_in[5];
    const float* bv   = (const float*)d_in[6];
    const float* Wo   = (const float*)d_in[7];
    const float* bo   = (const float*)d_in[8];
    const float* W1   = (const float*)d_in[9];
    const float* b1   = (const float*)d_in[10];
    const float* W2   = (const float*)d_in[11];
    const float* b2   = (const float*)d_in[12];
    const float* ln1g = (const float*)d_in[13];
    const float* ln1b = (const float*)d_in[14];
    const float* ln2g = (const float*)d_in[15];
    const float* ln2b = (const float*)d_in[16];

    char* ws = (char*)d_ws;
    const size_t MB = 1024 * 1024;
    bf16* WTq  = (bf16*)(ws + 0 * MB);
    bf16* WTk  = (bf16*)(ws + 2 * MB);
    bf16* WTv  = (bf16*)(ws + 4 * MB);
    bf16* WTo  = (bf16*)(ws + 6 * MB);
    bf16* WT1  = (bf16*)(ws + 8 * MB);
    bf16* WT2  = (bf16*)(ws + 16 * MB);
    bf16* hbuf = (bf16*)(ws + 24 * MB);
    bf16* VhT  = (bf16*)(ws + 24 * MB);
    bf16* Qh   = (bf16*)(ws + 40 * MB);
    bf16* Kh   = (bf16*)(ws + 56 * MB);
    bf16* Vh   = (bf16*)(ws + 72 * MB);
    bf16* attn = (bf16*)(ws + 88 * MB);
    bf16* ff1  = (bf16*)(ws + 40 * MB);
    float* x2  = (float*)d_out;

    dim3 tb(32, 8);
    transpose_cast4<<<dim3(32, 32, 4), tb, 0, stream>>>(Wq, Wk, Wv, Wo, WTq, WTk, WTv, WTo);
    transpose_cast<<<dim3(128, 32), tb, 0, stream>>>(W1, WT1, 1024, 4096);
    transpose_cast<<<dim3(32, 128), tb, 0, stream>>>(W2, WT2, 4096, 1024);

    ln_kernel<<<NTOK, 256, 0, stream>>>(x, ln1g, ln1b, hbuf);

    // fused QKV: 256x128 tile -> 32x24 = 768 blocks = 3 full occupancy rounds
    gemm256n128<0><<<dim3(32, 24), 512, 0, stream>>>(hbuf, WTq, bq, bk, bv, nullptr, Qh, NTOK, 3072, 1024);

    transpose_v<<<dim3(32, 64), 256, 0, stream>>>(Vh, VhT);

    attn_kernel<<<dim3(64, 8), 256, 0, stream>>>(Qh, Kh, VhT, attn);

    // O-proj: 256x128 -> 256 blocks = full GPU
    gemm256n128<1><<<dim3(32, 8), 512, 0, stream>>>(attn, WTo, bo, nullptr, nullptr, x, x2, NTOK, 1024, 1024);

    ln_kernel<<<NTOK, 256, 0, stream>>>(x2, ln2g, ln2b, hbuf);

    // FF1: 256^2 8-phase, 512 blocks = 2 full occupancy rounds
    gemm256<2><<<dim3(32, 16), 512, 0, stream>>>(hbuf, WT1, b1, nullptr, nullptr, nullptr, ff1, NTOK, 4096, 1024);
    // FF2: 256x128 -> 256 blocks = full GPU, K=4096 deep pipeline
    gemm256n128<1><<<dim3(32, 8), 512, 0, stream>>>(ff1, WT2, b2, nullptr, nullptr, x2, x2, NTOK, 1024, 4096);
}

// Round 4
// 468.151 us; speedup vs baseline: 1.1248x; 1.0465x over previous
//
#include <hip/hip_runtime.h>
#include <hip/hip_bf16.h>

typedef __bf16 bf16;
typedef __attribute__((ext_vector_type(8))) __bf16 bf16x8;
typedef __attribute__((ext_vector_type(4))) float f32x4;

#define D_MODEL 1024
#define NHEADS  16
#define DK      64
#define DFF     4096
#define BATCH   4
#define SEQ     2048
#define NTOK    (BATCH*SEQ)   // 8192
#define QSCALE  0.18033688011112042f   // 0.125 * log2(e)

#if __has_builtin(__builtin_amdgcn_exp2f)
#define EXP2F(x) __builtin_amdgcn_exp2f(x)   // raw v_exp_f32: no OCML denorm fixup
#else
#define EXP2F(x) exp2f(x)
#endif

__device__ __forceinline__ void gload16(const bf16* g, bf16* l) {
    __builtin_amdgcn_global_load_lds((const __attribute__((address_space(1))) void*)g,
                                     (__attribute__((address_space(3))) void*)l, 16, 0, 0);
}

// ---------------------------------------------------------------- transpose+cast (4x 1024^2 fused on z)
__global__ __launch_bounds__(256) void transpose_cast4(
    const float* __restrict__ W0, const float* __restrict__ W1,
    const float* __restrict__ W2, const float* __restrict__ W3,
    bf16* __restrict__ T0, bf16* __restrict__ T1,
    bf16* __restrict__ T2, bf16* __restrict__ T3)
{
    const int z = blockIdx.z;
    const float* W = (z == 0) ? W0 : (z == 1) ? W1 : (z == 2) ? W2 : W3;
    bf16*       Wt = (z == 0) ? T0 : (z == 1) ? T1 : (z == 2) ? T2 : T3;
    const int K = 1024, N = 1024;
    __shared__ float tile[32][33];
    const int tx = threadIdx.x, ty = threadIdx.y;
    const int n0 = blockIdx.x * 32, k0 = blockIdx.y * 32;
#pragma unroll
    for (int i = 0; i < 4; ++i)
        tile[ty + i*8][tx] = W[(size_t)(k0 + ty + i*8) * N + n0 + tx];
    __syncthreads();
#pragma unroll
    for (int i = 0; i < 4; ++i)
        Wt[(size_t)(n0 + ty + i*8) * K + k0 + tx] = (bf16)tile[tx][ty + i*8];
}

__global__ __launch_bounds__(256) void transpose_cast(
    const float* __restrict__ W, bf16* __restrict__ Wt, int K, int N)
{
    __shared__ float tile[32][33];
    const int tx = threadIdx.x, ty = threadIdx.y;
    const int n0 = blockIdx.x * 32, k0 = blockIdx.y * 32;
#pragma unroll
    for (int i = 0; i < 4; ++i)
        tile[ty + i*8][tx] = W[(size_t)(k0 + ty + i*8) * N + n0 + tx];
    __syncthreads();
#pragma unroll
    for (int i = 0; i < 4; ++i)
        Wt[(size_t)(n0 + ty + i*8) * K + k0 + tx] = (bf16)tile[tx][ty + i*8];
}

// ---------------------------------------------------------------- V head-transpose
// Vh[bh][s][64] -> VhT[bh][64][2048]
__global__ __launch_bounds__(256) void transpose_v(
    const bf16* __restrict__ V, bf16* __restrict__ VT)
{
    __shared__ bf16 t[64][72];
    const int bh = blockIdx.y;
    const int s0 = blockIdx.x * 64;
    const int r  = threadIdx.x >> 2;         // 0..63
    const int c0 = (threadIdx.x & 3) * 16;   // 0,16,32,48
    const bf16* Vb = V  + (size_t)bh * SEQ * DK;
    bf16*       Tb = VT + (size_t)bh * DK * SEQ;
#pragma unroll
    for (int i = 0; i < 2; ++i) {
        bf16x8 v = *(const bf16x8*)&Vb[(size_t)(s0 + r) * DK + c0 + i*8];
#pragma unroll
        for (int j = 0; j < 8; ++j) t[c0 + i*8 + j][r] = v[j];
    }
    __syncthreads();
#pragma unroll
    for (int i = 0; i < 2; ++i) {
        bf16x8 o;
#pragma unroll
        for (int j = 0; j < 8; ++j) o[j] = t[r][c0 + i*8 + j];
        *(bf16x8*)&Tb[(size_t)r * SEQ + s0 + c0 + i*8] = o;
    }
}

// ---------------------------------------------------------------- layernorm (fp32 in, bf16 out)
__global__ __launch_bounds__(256) void ln_kernel(
    const float* __restrict__ x, const float* __restrict__ g,
    const float* __restrict__ beta, bf16* __restrict__ out)
{
    const int row = blockIdx.x, tid = threadIdx.x;
    const f32x4* xr = (const f32x4*)(x + (size_t)row * D_MODEL);
    f32x4 v = xr[tid];
    float s  = v[0] + v[1] + v[2] + v[3];
    float s2 = v[0]*v[0] + v[1]*v[1] + v[2]*v[2] + v[3]*v[3];
#pragma unroll
    for (int off = 32; off > 0; off >>= 1) {
        s  += __shfl_down(s,  off, 64);
        s2 += __shfl_down(s2, off, 64);
    }
    __shared__ float red[8];
    const int wave = tid >> 6, lane = tid & 63;
    if (lane == 0) { red[wave] = s; red[wave + 4] = s2; }
    __syncthreads();
    if (tid == 0) {
        float a = red[0] + red[1] + red[2] + red[3];
        float c = red[4] + red[5] + red[6] + red[7];
        float mu  = a * (1.0f / D_MODEL);
        float var = c * (1.0f / D_MODEL) - mu * mu;
        red[0] = mu;
        red[1] = rsqrtf(var + 1e-5f);
    }
    __syncthreads();
    const float mu = red[0], rs = red[1];
    f32x4 gv = ((const f32x4*)g)[tid];
    f32x4 bv = ((const f32x4*)beta)[tid];
    union { bf16 h[4]; uint2 u; } o;
#pragma unroll
    for (int i = 0; i < 4; ++i) o.h[i] = (bf16)((v[i] - mu) * rs * gv[i] + bv[i]);
    *(uint2*)(out + (size_t)row * D_MODEL + tid * 4) = o.u;
}

#define PH_WAIT() do { \
    __builtin_amdgcn_s_barrier(); \
    asm volatile("s_waitcnt lgkmcnt(0)" ::: "memory"); \
    __builtin_amdgcn_sched_barrier(0); \
} while (0)

// ---------------------------------------------------------------- bf16 GEMM, 256x256 tile, BK=64, 8-wave 8-phase
// (used where gridDim is a multiple of 256 blocks: FF1)
template<int EPI>
__global__ __launch_bounds__(512, 2) void gemm256(
    const bf16* __restrict__ A, const bf16* __restrict__ Bt,
    const float* __restrict__ bias, const float* __restrict__ bias2,
    const float* __restrict__ bias3, const float* __restrict__ resid,
    void* __restrict__ outp, int M, int N, int K)
{
    __shared__ __align__(16) bf16 smem[65536];   // 128 KiB
    const int tid  = threadIdx.x;
    const int wave = tid >> 6, lane = tid & 63;
    const int quad = lane >> 4, l16 = lane & 15;
    const int wr = wave >> 2, wcn = wave & 3;    // 2 x 4 wave grid; per-wave C = 128x64
    const int m0 = blockIdx.x * 256, n0 = blockIdx.y * 256;
    const int NT = K >> 6;

    const bf16* gA[2]; const bf16* gB[2]; int ldsOff[2];
#pragma unroll
    for (int l = 0; l < 2; ++l) {
        const int slot = tid + l * 512;
        const int r = slot >> 2;
        const int clog = (slot & 3) ^ ((r >> 1) & 3);
        gA[l] = A  + (size_t)(m0 + r) * K + clog * 8;
        gB[l] = Bt + (size_t)(n0 + r) * K + clog * 8;
        ldsOff[l] = (wave * 64 + l * 512) * 8;
    }

    auto stageA = [&](int buf, int t, int kk) {
        bf16* dst = smem + (buf * 2 + kk) * 8192;
#pragma unroll
        for (int l = 0; l < 2; ++l) gload16(gA[l] + t * 64 + kk * 32, dst + ldsOff[l]);
    };
    auto stageB = [&](int buf, int t, int kk) {
        bf16* dst = smem + 32768 + (buf * 2 + kk) * 8192;
#pragma unroll
        for (int l = 0; l < 2; ++l) gload16(gB[l] + t * 64 + kk * 32, dst + ldsOff[l]);
    };

    const int cswz  = (quad ^ ((l16 >> 1) & 3)) * 8;
    const int aBase = (wr * 128 + l16) * 32 + cswz;
    const int bBase = (wcn * 64 + l16) * 32 + cswz;

    f32x4 acc[8][4];
    const f32x4 vzero = {0.f, 0.f, 0.f, 0.f};
#pragma unroll
    for (int i = 0; i < 8; ++i)
#pragma unroll
        for (int j = 0; j < 4; ++j) acc[i][j] = vzero;

    stageA(0, 0, 0); stageB(0, 0, 0);
    stageA(0, 0, 1); stageB(0, 0, 1);
    if (NT > 1) {
        stageA(1, 1, 0); stageB(1, 1, 0);
        asm volatile("s_waitcnt vmcnt(4)" ::: "memory");
    } else {
        asm volatile("s_waitcnt vmcnt(0)" ::: "memory");
    }
    __builtin_amdgcn_s_barrier();

    bf16x8 af[4], bfr[4];
#define GMM_MFMA(mh) do { \
    __builtin_amdgcn_s_setprio(1); \
    _Pragma("unroll") \
    for (int i_ = 0; i_ < 4; ++i_) { \
        _Pragma("unroll") \
        for (int j_ = 0; j_ < 4; ++j_) \
            acc[(mh)*4 + i_][j_] = __builtin_amdgcn_mfma_f32_16x16x32_bf16(af[i_], bfr[j_], acc[(mh)*4 + i_][j_], 0, 0, 0); \
    } \
    __builtin_amdgcn_s_setprio(0); \
    __builtin_amdgcn_s_barrier(); \
} while (0)

#pragma unroll 1
    for (int t = 0; t < NT; ++t) {
        const int buf = t & 1;
        const bf16* As0 = smem + buf * 16384;
        const bf16* As1 = As0 + 8192;
        const bf16* Bs0 = smem + 32768 + buf * 16384;
        const bf16* Bs1 = Bs0 + 8192;

#pragma unroll
        for (int i = 0; i < 4; ++i) af[i]  = *(const bf16x8*)&As0[aBase + i * 512];
#pragma unroll
        for (int j = 0; j < 4; ++j) bfr[j] = *(const bf16x8*)&Bs0[bBase + j * 512];
        if (t + 1 < NT) stageA(buf ^ 1, t + 1, 1);
        PH_WAIT();
        GMM_MFMA(0);

#pragma unroll
        for (int i = 0; i < 4; ++i) af[i] = *(const bf16x8*)&As0[aBase + 2048 + i * 512];
        if (t + 1 < NT) stageB(buf ^ 1, t + 1, 1);
        PH_WAIT();
        GMM_MFMA(1);

#pragma unroll
        for (int i = 0; i < 4; ++i) af[i]  = *(const bf16x8*)&As1[aBase + 2048 + i * 512];
#pragma unroll
        for (int j = 0; j < 4; ++j) bfr[j] = *(const bf16x8*)&Bs1[bBase + j * 512];
        if (t + 2 < NT) stageA(buf, t + 2, 0);
        PH_WAIT();
        GMM_MFMA(1);

#pragma unroll
        for (int i = 0; i < 4; ++i) af[i] = *(const bf16x8*)&As1[aBase + i * 512];
        if (t + 2 < NT) {
            stageB(buf, t + 2, 0);
            asm volatile("s_waitcnt vmcnt(4)" ::: "memory");
        } else {
            asm volatile("s_waitcnt vmcnt(0)" ::: "memory");
        }
        PH_WAIT();
        GMM_MFMA(0);
    }
#undef GMM_MFMA

#pragma unroll
    for (int mf = 0; mf < 8; ++mf) {
#pragma unroll
        for (int nf = 0; nf < 4; ++nf) {
            const int col = n0 + wcn * 64 + nf * 16 + l16;
            float bcol, sc = 1.0f;
            if (EPI == 0) {
                const int seg = col >> 10;
                const float* bp = (seg == 0) ? bias : ((seg == 1) ? bias2 : bias3);
                bcol = bp[col & 1023];
                if (seg == 0) sc = QSCALE;
            } else {
                bcol = bias[col];
            }
#pragma unroll
            for (int r = 0; r < 4; ++r) {
                const int row = m0 + wr * 128 + mf * 16 + quad * 4 + r;
                const float v = acc[mf][nf][r] + bcol;
                if (EPI == 0) {
                    const int bb = row >> 11, ss = row & (SEQ - 1);
                    const int hh = (col & 1023) >> 6, dd = col & (DK - 1);
                    const size_t seg = (size_t)(col >> 10);
                    ((bf16*)outp)[seg * 8388608 + (((size_t)(bb * NHEADS + hh)) * SEQ + ss) * DK + dd] = (bf16)(v * sc);
                } else if (EPI == 1) {
                    const size_t idx = (size_t)row * N + col;
                    ((float*)outp)[idx] = v + resid[idx];
                } else {
                    ((bf16*)outp)[(size_t)row * N + col] = (bf16)fmaxf(v, 0.f);
                }
            }
        }
    }
}

// ---------------------------------------------------------------- bf16 GEMM, 256x128 tile, BK=64, 8-wave, 2 phases/K-tile
template<int EPI>
__global__ __launch_bounds__(512, 2) void gemm256n128(
    const bf16* __restrict__ A, const bf16* __restrict__ Bt,
    const float* __restrict__ bias, const float* __restrict__ bias2,
    const float* __restrict__ bias3, const float* __restrict__ resid,
    void* __restrict__ outp, int M, int N, int K)
{
    __shared__ __align__(16) bf16 smem[49152];   // 96 KiB
    const int tid  = threadIdx.x;
    const int wave = tid >> 6, lane = tid & 63;
    const int quad = lane >> 4, l16 = lane & 15;
    const int wr = wave >> 1, wcn = wave & 1;    // 4 x 2 wave grid; per-wave C = 64x64
    const int m0 = blockIdx.x * 256, n0 = blockIdx.y * 128;
    const int NT = K >> 6;

    const bf16* gA[2]; const bf16* gB0; int ldsOffA[2];
#pragma unroll
    for (int l = 0; l < 2; ++l) {
        const int slot = tid + l * 512;
        const int r = slot >> 2;
        const int clog = (slot & 3) ^ ((r >> 1) & 3);
        gA[l] = A + (size_t)(m0 + r) * K + clog * 8;
        ldsOffA[l] = (wave * 64 + l * 512) * 8;
    }
    {
        const int r = tid >> 2;
        const int clog = (tid & 3) ^ ((r >> 1) & 3);
        gB0 = Bt + (size_t)(n0 + r) * K + clog * 8;
    }
    const int ldsOffB = wave * 512;

    auto stageA = [&](int buf, int t, int kk) {
        bf16* dst = smem + (buf * 2 + kk) * 8192;
#pragma unroll
        for (int l = 0; l < 2; ++l) gload16(gA[l] + t * 64 + kk * 32, dst + ldsOffA[l]);
    };
    auto stageB = [&](int buf, int t, int kk) {
        bf16* dst = smem + 32768 + (buf * 2 + kk) * 4096;
        gload16(gB0 + t * 64 + kk * 32, dst + ldsOffB);
    };

    const int cswz  = (quad ^ ((l16 >> 1) & 3)) * 8;
    const int aBase = (wr * 64 + l16) * 32 + cswz;
    const int bBase = (wcn * 64 + l16) * 32 + cswz;

    f32x4 acc[4][4];
    const f32x4 vzero = {0.f, 0.f, 0.f, 0.f};
#pragma unroll
    for (int i = 0; i < 4; ++i)
#pragma unroll
        for (int j = 0; j < 4; ++j) acc[i][j] = vzero;

    stageA(0, 0, 0); stageB(0, 0, 0);
    stageA(0, 0, 1); stageB(0, 0, 1);
    if (NT > 1) {
        stageA(1, 1, 0); stageB(1, 1, 0);
        asm volatile("s_waitcnt vmcnt(3)" ::: "memory");
    } else {
        asm volatile("s_waitcnt vmcnt(0)" ::: "memory");
    }
    __builtin_amdgcn_s_barrier();

    bf16x8 af[4], bfr[4];
#define GMM_MFMA16() do { \
    __builtin_amdgcn_s_setprio(1); \
    _Pragma("unroll") \
    for (int i_ = 0; i_ < 4; ++i_) { \
        _Pragma("unroll") \
        for (int j_ = 0; j_ < 4; ++j_) \
            acc[i_][j_] = __builtin_amdgcn_mfma_f32_16x16x32_bf16(af[i_], bfr[j_], acc[i_][j_], 0, 0, 0); \
    } \
    __builtin_amdgcn_s_setprio(0); \
    __builtin_amdgcn_s_barrier(); \
} while (0)

#pragma unroll 1
    for (int t = 0; t < NT; ++t) {
        const int buf = t & 1;
        const bf16* As0 = smem + buf * 16384;
        const bf16* As1 = As0 + 8192;
        const bf16* Bs0 = smem + 32768 + buf * 8192;
        const bf16* Bs1 = Bs0 + 4096;

#pragma unroll
        for (int i = 0; i < 4; ++i) af[i]  = *(const bf16x8*)&As0[aBase + i * 512];
#pragma unroll
        for (int j = 0; j < 4; ++j) bfr[j] = *(const bf16x8*)&Bs0[bBase + j * 512];
        if (t + 1 < NT) { stageA(buf ^ 1, t + 1, 1); stageB(buf ^ 1, t + 1, 1); }
        PH_WAIT();
        GMM_MFMA16();

#pragma unroll
        for (int i = 0; i < 4; ++i) af[i]  = *(const bf16x8*)&As1[aBase + i * 512];
#pragma unroll
        for (int j = 0; j < 4; ++j) bfr[j] = *(const bf16x8*)&Bs1[bBase + j * 512];
        if (t + 2 < NT) {
            stageA(buf, t + 2, 0); stageB(buf, t + 2, 0);
            asm volatile("s_waitcnt vmcnt(3)" ::: "memory");
        } else {
            asm volatile("s_waitcnt vmcnt(0)" ::: "memory");
        }
        PH_WAIT();
        GMM_MFMA16();
    }
#undef GMM_MFMA16

#pragma unroll
    for (int mf = 0; mf < 4; ++mf) {
#pragma unroll
        for (int nf = 0; nf < 4; ++nf) {
            const int col = n0 + wcn * 64 + nf * 16 + l16;
            float bcol, sc = 1.0f;
            if (EPI == 0) {
                const int seg = col >> 10;
                const float* bp = (seg == 0) ? bias : ((seg == 1) ? bias2 : bias3);
                bcol = bp[col & 1023];
                if (seg == 0) sc = QSCALE;
            } else {
                bcol = bias[col];
            }
#pragma unroll
            for (int r = 0; r < 4; ++r) {
                const int row = m0 + wr * 64 + mf * 16 + quad * 4 + r;
                const float v = acc[mf][nf][r] + bcol;
                if (EPI == 0) {
                    const int bb = row >> 11, ss = row & (SEQ - 1);
                    const int hh = (col & 1023) >> 6, dd = col & (DK - 1);
                    const size_t seg = (size_t)(col >> 10);
                    ((bf16*)outp)[seg * 8388608 + (((size_t)(bb * NHEADS + hh)) * SEQ + ss) * DK + dd] = (bf16)(v * sc);
                } else if (EPI == 1) {
                    const size_t idx = (size_t)row * N + col;
                    ((float*)outp)[idx] = v + resid[idx];
                } else {
                    ((bf16*)outp)[(size_t)row * N + col] = (bf16)fmaxf(v, 0.f);
                }
            }
        }
    }
}

// ---------------------------------------------------------------- flash attention (causal), S^T layout
// In-register P relayout (permlane32_swap + xor16 shuffle); defer-max (THR=8, log2 units);
// raw v_exp_f32 via builtin (no OCML denorm fixup); setprio around MFMA clusters (T5).
__global__ __launch_bounds__(256, 2) void attn_kernel(
    const bf16* __restrict__ Q, const bf16* __restrict__ K,
    const bf16* __restrict__ VT, bf16* __restrict__ out)
{
    const int bh = blockIdx.x;
    const int b = bh >> 4, h = bh & 15;
    const int tid  = threadIdx.x;
    const int wave = tid >> 6, lane = tid & 63;
    const int quad = lane >> 4, l16 = lane & 15;

    __shared__ __align__(16) bf16 smem[32768 + 4 * 1152];
    bf16* Pw = smem + 32768 + wave * 1152;   // epilogue-only

    const bf16* Qb = Q  + (size_t)bh * SEQ * DK;
    const bf16* Kb = K  + (size_t)bh * SEQ * DK;
    const bf16* Vb = VT + (size_t)bh * DK * SEQ;

    int goK[4], goV[4], lo[4];
#pragma unroll
    for (int i = 0; i < 4; ++i) {
        const int U = (wave * 4 + i) * 64 + lane;
        const int rK = U >> 3, uK = (U & 7) ^ (rK & 7);
        goK[i] = rK * DK + uK * 8;
        const int rV = U >> 4, usw = U & 15;
        const int uV = (usw & 8) | ((usw & 7) ^ (rV & 7));
        goV[i] = rV * SEQ + uV * 8;
        lo[i]  = (wave * 4 + i) * 512;
    }

    auto stage = [&](int buf, int t) {
        const bf16* kp = Kb + (size_t)(t * 128) * DK;
        const bf16* vp = Vb + t * 128;
        bf16* kb = smem + buf * 8192;
        bf16* vb = smem + 16384 + buf * 8192;
#pragma unroll
        for (int i = 0; i < 4; ++i) gload16(kp + goK[i], kb + lo[i]);
#pragma unroll
        for (int i = 0; i < 4; ++i) gload16(vp + goV[i], vb + lo[i]);
    };

    const f32x4 vzero = {0.f, 0.f, 0.f, 0.f};
    int g = 0;
    stage(0, 0);

    for (int phase = 0; phase < 2; ++phase) {
        const int qt = phase ? (int)blockIdx.y : 15 - (int)blockIdx.y;
        const int qw = qt * 128 + wave * 32;

        bf16x8 qf[2][2];
#pragma unroll
        for (int qi = 0; qi < 2; ++qi)
#pragma unroll
            for (int kk = 0; kk < 2; ++kk)
                qf[qi][kk] = *(const bf16x8*)&Qb[(size_t)(qw + qi*16 + l16) * DK + kk*32 + quad*8];

        f32x4 Oacc[2][4];
        float m_[2], l_[2];
#pragma unroll
        for (int qi = 0; qi < 2; ++qi) {
            m_[qi] = -1.0e30f; l_[qi] = 0.f;
#pragma unroll
            for (int dj = 0; dj < 4; ++dj) Oacc[qi][dj] = vzero;
        }

        for (int t = 0; t <= qt; ++t, ++g) {
            const int cur = g & 1;
            __syncthreads();
            if (t < qt)            stage(cur ^ 1, t + 1);
            else if (phase == 0)   stage(cur ^ 1, 0);
            const bf16* kb = smem + cur * 8192;
            const bf16* vb = smem + 16384 + cur * 8192;
            const int kv0 = t * 128;

            f32x4 sv[8][2];
#pragma unroll
            for (int kvt = 0; kvt < 8; ++kvt) {
                const int R = kvt*16 + l16, rx = R & 7;
                bf16x8 kf0 = *(const bf16x8*)&kb[R*64 + (quad ^ rx)*8];
                bf16x8 kf1 = *(const bf16x8*)&kb[R*64 + (((quad + 4) & 7) ^ rx)*8];
                __builtin_amdgcn_s_setprio(1);
#pragma unroll
                for (int qi = 0; qi < 2; ++qi) {
                    f32x4 tacc = vzero;
                    tacc = __builtin_amdgcn_mfma_f32_16x16x32_bf16(kf0, qf[qi][0], tacc, 0, 0, 0);
                    tacc = __builtin_amdgcn_mfma_f32_16x16x32_bf16(kf1, qf[qi][1], tacc, 0, 0, 0);
                    sv[kvt][qi] = tacc;
                }
                __builtin_amdgcn_s_setprio(0);
            }

            if (t == qt) {   // diagonal: causal mask
#pragma unroll
                for (int kvt = 0; kvt < 8; ++kvt)
#pragma unroll
                    for (int qi = 0; qi < 2; ++qi)
#pragma unroll
                        for (int r = 0; r < 4; ++r) {
                            const int kv = kv0 + kvt*16 + quad*4 + r;
                            const int q  = qw + qi*16 + l16;
                            if (kv > q) sv[kvt][qi][r] = -1.0e30f;
                        }
            }

            // tile max per q-row (max3-friendly trees), quad-group reduce
            float mx[2];
#pragma unroll
            for (int qi = 0; qi < 2; ++qi) {
                float hx[8];
#pragma unroll
                for (int kvt = 0; kvt < 8; ++kvt)
                    hx[kvt] = fmaxf(fmaxf(fmaxf(sv[kvt][qi][0], sv[kvt][qi][1]), sv[kvt][qi][2]), sv[kvt][qi][3]);
                float m4 = fmaxf(fmaxf(fmaxf(hx[0], hx[1]), hx[2]), hx[3]);
                m4 = fmaxf(fmaxf(fmaxf(m4, hx[4]), fmaxf(hx[5], hx[6])), hx[7]);
                m4 = fmaxf(m4, __shfl_xor(m4, 16, 64));
                mx[qi] = fmaxf(m4, __shfl_xor(m4, 32, 64));
            }

            // defer-max: only rescale when the tile max exceeds running max by > 8 (log2)
            if (__any((mx[0] > m_[0] + 8.f) || (mx[1] > m_[1] + 8.f))) {
#pragma unroll
                for (int qi = 0; qi < 2; ++qi) {
                    const float newm  = fmaxf(m_[qi], mx[qi]);
                    const float alpha = EXP2F(m_[qi] - newm);
                    m_[qi] = newm;
                    l_[qi] *= alpha;
#pragma unroll
                    for (int dj = 0; dj < 4; ++dj) Oacc[qi][dj] *= alpha;
                }
            }

            // exponentiate + row-sum (P bounded by 2^8)
#pragma unroll
            for (int qi = 0; qi < 2; ++qi) {
                float rs = 0.f;
#pragma unroll
                for (int kvt = 0; kvt < 8; ++kvt)
#pragma unroll
                    for (int r = 0; r < 4; ++r) {
                        const float p = EXP2F(sv[kvt][qi][r] - m_[qi]);
                        sv[kvt][qi][r] = p;
                        rs += p;
                    }
                rs += __shfl_xor(rs, 16, 64);
                rs += __shfl_xor(rs, 32, 64);
                l_[qi] += rs;
            }

            // O^T += V^T·P^T in 32-kv chunks; P relayout fully in-register
#pragma unroll
            for (int c2 = 0; c2 < 4; ++c2) {
                bf16x8 vf[4];
#pragma unroll
                for (int dj = 0; dj < 4; ++dj) {
                    const int R = dj*16 + l16;
                    const int u = c2*4 + quad;
                    const int usw = (u & 8) | ((u & 7) ^ (R & 7));
                    vf[dj] = *(const bf16x8*)&vb[R*128 + usw*8];
                }
#pragma unroll
                for (int qi = 0; qi < 2; ++qi) {
                    const f32x4 A = sv[c2*2 + 0][qi];
                    const f32x4 B = sv[c2*2 + 1][qi];
                    union { bf16 h[2]; int u; } pA01, pA23, pB01, pB23;
                    pA01.h[0] = (bf16)A[0]; pA01.h[1] = (bf16)A[1];
                    pA23.h[0] = (bf16)A[2]; pA23.h[1] = (bf16)A[3];
                    pB01.h[0] = (bf16)B[0]; pB01.h[1] = (bf16)B[1];
                    pB23.h[0] = (bf16)B[2]; pB23.h[1] = (bf16)B[3];
                    int a01 = pA01.u, a23 = pA23.u, b01 = pB01.u, b23 = pB23.u;
                    asm volatile("v_permlane32_swap_b32 %0, %1" : "+v"(a01), "+v"(b01));
                    asm volatile("v_permlane32_swap_b32 %0, %1" : "+v"(a23), "+v"(b23));
                    const int x01 = __shfl_xor(b01, 16, 64);
                    const int x23 = __shfl_xor(b23, 16, 64);
                    const int y01 = __shfl_xor(a01, 16, 64);
                    const int y23 = __shfl_xor(a23, 16, 64);
                    const bool odd = (quad & 1) != 0;
                    union { int w[4]; bf16x8 v; } pf;
                    pf.w[0] = odd ? x01 : a01;
                    pf.w[1] = odd ? x23 : a23;
                    pf.w[2] = odd ? b01 : y01;
                    pf.w[3] = odd ? b23 : y23;
                    __builtin_amdgcn_s_setprio(1);
#pragma unroll
                    for (int dj = 0; dj < 4; ++dj)
                        Oacc[qi][dj] = __builtin_amdgcn_mfma_f32_16x16x32_bf16(vf[dj], pf.v, Oacc[qi][dj], 0, 0, 0);
                    __builtin_amdgcn_s_setprio(0);
                }
            }
        }

        // phase epilogue through private Pw (no barrier): chunked [32 q][32 d] halves
        const float inv0 = 1.0f / l_[0], inv1 = 1.0f / l_[1];
#pragma unroll
        for (int dh = 0; dh < 2; ++dh) {
#pragma unroll
            for (int qi = 0; qi < 2; ++qi) {
                const float inv = qi ? inv1 : inv0;
#pragma unroll
                for (int djl = 0; djl < 2; ++djl) {
                    const int dj = dh*2 + djl;
                    union { bf16 h[4]; unsigned long long u; } ok;
#pragma unroll
                    for (int r = 0; r < 4; ++r) ok.h[r] = (bf16)(Oacc[qi][dj][r] * inv);
                    *(unsigned long long*)&Pw[(qi*16 + l16)*36 + djl*16 + quad*4] = ok.u;
                }
            }
            const int row = lane >> 1;
#pragma unroll
            for (int it = 0; it < 2; ++it) {
                const int grp = (lane & 1) + 2*it;
                bf16x8 o = *(const bf16x8*)&Pw[row*36 + grp*8];
                *(bf16x8*)&out[((size_t)(b*SEQ + qw - wave*32 + wave*32 + row))*D_MODEL + h*DK + dh*32 + grp*8] = o;
            }
        }
    }
}

// ---------------------------------------------------------------- launch
extern "C" void kernel_launch(void* const* d_in, const int* in_sizes, int n_in,
                              void* d_out, int out_size, void* d_ws, size_t ws_size,
                              hipStream_t stream)
{
    const float* x    = (const float*)d_in[0];
    const float* Wq   = (const float*)d_in[1];
    const float* bq   = (const float*)d_in[2];
    const float* Wk   = (const float*)d_in[3];
    const float* bk   = (const float*)d_in[4];
    const float* Wv   = (const float*)d_in[5];
    const float* bv   = (const float*)d_in[6];
    const float* Wo   = (const float*)d_in[7];
    const float* bo   = (const float*)d_in[8];
    const float* W1   = (const float*)d_in[9];
    const float* b1   = (const float*)d_in[10];
    const float* W2   = (const float*)d_in[11];
    const float* b2   = (const float*)d_in[12];
    const float* ln1g = (const float*)d_in[13];
    const float* ln1b = (const float*)d_in[14];
    const float* ln2g = (const float*)d_in[15];
    const float* ln2b = (const float*)d_in[16];

    char* ws = (char*)d_ws;
    const size_t MB = 1024 * 1024;
    bf16* WTq  = (bf16*)(ws + 0 * MB);
    bf16* WTk  = (bf16*)(ws + 2 * MB);
    bf16* WTv  = (bf16*)(ws + 4 * MB);
    bf16* WTo  = (bf16*)(ws + 6 * MB);
    bf16* WT1  = (bf16*)(ws + 8 * MB);
    bf16* WT2  = (bf16*)(ws + 16 * MB);
    bf16* hbuf = (bf16*)(ws + 24 * MB);
    bf16* VhT  = (bf16*)(ws + 24 * MB);
    bf16* Qh   = (bf16*)(ws + 40 * MB);
    bf16* Kh   = (bf16*)(ws + 56 * MB);
    bf16* Vh   = (bf16*)(ws + 72 * MB);
    bf16* attn = (bf16*)(ws + 88 * MB);
    bf16* ff1  = (bf16*)(ws + 40 * MB);
    float* x2  = (float*)d_out;

    dim3 tb(32, 8);
    transpose_cast4<<<dim3(32, 32, 4), tb, 0, stream>>>(Wq, Wk, Wv, Wo, WTq, WTk, WTv, WTo);
    transpose_cast<<<dim3(128, 32), tb, 0, stream>>>(W1, WT1, 1024, 4096);
    transpose_cast<<<dim3(32, 128), tb, 0, stream>>>(W2, WT2, 4096, 1024);

    ln_kernel<<<NTOK, 256, 0, stream>>>(x, ln1g, ln1b, hbuf);

    // fused QKV: 256x128 tile -> 32x24 = 768 blocks = 3 full occupancy rounds
    gemm256n128<0><<<dim3(32, 24), 512, 0, stream>>>(hbuf, WTq, bq, bk, bv, nullptr, Qh, NTOK, 3072, 1024);

    transpose_v<<<dim3(32, 64), 256, 0, stream>>>(Vh, VhT);

    attn_kernel<<<dim3(64, 8), 256, 0, stream>>>(Qh, Kh, VhT, attn);

    // O-proj: 256x128 -> 256 blocks = full GPU
    gemm256n128<1><<<dim3(32, 8), 512, 0, stream>>>(attn, WTo, bo, nullptr, nullptr, x, x2, NTOK, 1024, 1024);

    ln_kernel<<<NTOK, 256, 0, stream>>>(x2, ln2g, ln2b, hbuf);

    // FF1: 256^2 8-phase, 512 blocks = 2 full occupancy rounds
    gemm256<2><<<dim3(32, 16), 512, 0, stream>>>(hbuf, WT1, b1, nullptr, nullptr, nullptr, ff1, NTOK, 4096, 1024);
    // FF2: 256x128 -> 256 blocks = full GPU, K=4096 deep pipeline
    gemm256n128<1><<<dim3(32, 8), 512, 0, stream>>>(ff1, WT2, b2, nullptr, nullptr, x2, x2, NTOK, 1024, 4096);
}